// Round 4
// baseline (306.903 us; speedup 1.0000x reference)
//
#include <hip/hip_runtime.h>
#include <hip/hip_bf16.h>
#include <cstdint>

typedef __bf16 bf16;
typedef __bf16 bf16x8 __attribute__((ext_vector_type(8)));
typedef float floatx4 __attribute__((ext_vector_type(4)));

#define B_   4
#define L_   896
#define D_   2048
#define HQ_  32
#define HKV_ 8
#define HD_  64
#define NQKV 3072   /* 2048 q + 512 k + 512 v */
#define M_   3584   /* B_*L_ */

// async global->LDS, 16B per lane. LDS dst must be wave-uniform base + lane*16.
__device__ inline void gl_lds16(const bf16* g, bf16* l) {
    __builtin_amdgcn_global_load_lds(
        (const __attribute__((address_space(1))) void*)g,
        (__attribute__((address_space(3))) void*)l, 16, 0, 0);
}

__device__ inline void barrier_() {
    asm volatile("" ::: "memory");
    __builtin_amdgcn_s_barrier();
    asm volatile("" ::: "memory");
}

// ---------------------------------------------------------------------------
// fp32 -> bf16 (x only). Grid: n/1024 blocks.
// ---------------------------------------------------------------------------
__global__ __launch_bounds__(256) void convert_to_bf16(const float* __restrict__ in,
                                                       bf16* __restrict__ out) {
    long q = (long)blockIdx.x * 256 + threadIdx.x;
    float4 v = ((const float4*)in)[q];
    union { bf16 b[4]; ushort4 u; } w;
    w.b[0] = (bf16)v.x; w.b[1] = (bf16)v.y; w.b[2] = (bf16)v.z; w.b[3] = (bf16)v.w;
    ((ushort4*)out)[q] = w.u;
}

// ---------------------------------------------------------------------------
// RoPE cos/sin table: [L][32] float2
// ---------------------------------------------------------------------------
__global__ __launch_bounds__(256) void rope_cs_kernel(const int* __restrict__ pos_ids,
                                                      float2* __restrict__ cs) {
    int idx = blockIdx.x * 256 + threadIdx.x;
    if (idx >= L_ * 32) return;
    int l = idx >> 5, i = idx & 31;
    float p = (float)pos_ids[l];
    float inv = exp2f(-(float)i * (13.287712379549449f / 32.0f));  // 10000^(-i/32)
    float a = p * inv;
    cs[idx] = make_float2(cosf(a), sinf(a));
}

// ---------------------------------------------------------------------------
// Fused fp32->bf16 + 64x64 tiled transpose. in fp32 [R][C] -> out bf16 [C][R].
// ---------------------------------------------------------------------------
__global__ __launch_bounds__(256) void transpose_cvt(
    const float* __restrict__ in, ushort* __restrict__ out, int C, int R) {
    __shared__ ushort t[64][72];
    int tid = threadIdx.x;
    int tr = tid >> 4, tc = (tid & 15) << 2;
    long r0 = (long)blockIdx.y << 6, c0 = (long)blockIdx.x << 6;
#pragma unroll
    for (int i = 0; i < 4; ++i) {
        float4 v = *(const float4*)&in[(r0 + tr + i * 16) * C + c0 + tc];
        union { bf16 b[4]; ushort4 u; } w;
        w.b[0] = (bf16)v.x; w.b[1] = (bf16)v.y; w.b[2] = (bf16)v.z; w.b[3] = (bf16)v.w;
        *(ushort4*)&t[tr + i * 16][tc] = w.u;
    }
    __syncthreads();
#pragma unroll
    for (int i = 0; i < 4; ++i) {
        ushort4 w;
        w.x = t[tc + 0][tr + i * 16];
        w.y = t[tc + 1][tr + i * 16];
        w.z = t[tc + 2][tr + i * 16];
        w.w = t[tc + 3][tr + i * 16];
        *(ushort4*)&out[(c0 + tr + i * 16) * R + r0 + tc] = w;
    }
}

// ---------------------------------------------------------------------------
// bf16 64x64 tiled transpose (for V -> Vt). z-batch as before.
// ---------------------------------------------------------------------------
__global__ __launch_bounds__(256) void transpose_u16(
    const ushort* __restrict__ in, ushort* __restrict__ out,
    int ld_in, int ld_out, long is1, long is2, long os1, long os2) {
    __shared__ ushort t[64][72];
    int z = blockIdx.z;
    const ushort* ip = in + (long)(z >> 3) * is1 + (long)(z & 7) * is2;
    ushort* op = out + (long)(z >> 3) * os1 + (long)(z & 7) * os2;
    int tid = threadIdx.x;
    int tr = tid >> 4, tc = (tid & 15) << 2;
    long r0 = (long)blockIdx.y << 6, c0 = (long)blockIdx.x << 6;
#pragma unroll
    for (int i = 0; i < 4; ++i) {
        ushort4 v = *(const ushort4*)&ip[(r0 + tr + i * 16) * ld_in + c0 + tc];
        *(ushort4*)&t[tr + i * 16][tc] = v;
    }
    __syncthreads();
#pragma unroll
    for (int i = 0; i < 4; ++i) {
        ushort4 w;
        w.x = t[tc + 0][tr + i * 16];
        w.y = t[tc + 1][tr + i * 16];
        w.z = t[tc + 2][tr + i * 16];
        w.w = t[tc + 3][tr + i * 16];
        *(ushort4*)&op[(c0 + tr + i * 16) * ld_out + r0 + tc] = w;
    }
}

// ===========================================================================
// Shared GEMM helpers (3-bit slot-swizzled [128][64] bf16 LDS halves).
// Swizzle: a row is 8 x 16B slots; phys_slot = log_slot ^ (row & 7).
// Staging (rule #21): gl_lds writes linearly; lane l of wave w sources global
//   (row = 16w + (l>>3), col = ((l&7)^(l>>3))<<3); chunks +8 rows (0 mod 8).
// Read: fragment (row, ks*32+quad*8) -> col = ((ks*4+quad)^(row&7))<<3.
// ===========================================================================

template <int RQ, int RESPAN>
__device__ inline void lda_g(const bf16* p, int l16, int c0, int c1, bf16x8 (&af)[4][2]) {
#pragma unroll
    for (int i = 0; i < 4; ++i) {
        const bf16* rp = &p[(RQ * RESPAN + i * 16 + l16) * 64];
        af[i][0] = *(const bf16x8*)&rp[c0];
        af[i][1] = *(const bf16x8*)&rp[c1];
    }
}

template <int CQ>
__device__ inline void ldb_g(const bf16* p, int brow, int l16, int c0, int c1,
                             bf16x8 (&bq)[2][2]) {
#pragma unroll
    for (int j = 0; j < 2; ++j) {
        const bf16* rp = &p[(brow + (CQ * 2 + j) * 16 + l16) * 64];
        bq[j][0] = *(const bf16x8*)&rp[c0];
        bq[j][1] = *(const bf16x8*)&rp[c1];
    }
}

__device__ inline void stage_half(const bf16* gsrc, bf16* ldst, long rowK) {
    gl_lds16(gsrc,            ldst);
    gl_lds16(gsrc + 8 * rowK, ldst + 512);
}

// ===========================================================================
// 256x256 8-phase GEMM (m201-style): C[M][N] = A[M][K] * Bt[N][K]^T.
// 8 waves (2Mx4N), BK=64, 128 KiB dbuf LDS, counted vmcnt, setprio.
// Optional fused RoPE epilogue (ropeflag): cols n<2560 get rotary applied;
// pair = adjacent l16 lanes -> one __shfl_xor. Block-uniform (n0 % 256 == 0,
// 2560 = 10*256) so no divergence.
// ===========================================================================
template <int RQ, int CQ>
__device__ inline void mma8(const bf16x8 (&af)[4][2], const bf16x8 (&bq)[2][2],
                            floatx4 (&acc)[8][4]) {
#pragma unroll
    for (int i = 0; i < 4; ++i)
#pragma unroll
        for (int j = 0; j < 2; ++j) {
            floatx4 c = acc[RQ * 4 + i][CQ * 2 + j];
            c = __builtin_amdgcn_mfma_f32_16x16x32_bf16(af[i][0], bq[j][0], c, 0, 0, 0);
            c = __builtin_amdgcn_mfma_f32_16x16x32_bf16(af[i][1], bq[j][1], c, 0, 0, 0);
            acc[RQ * 4 + i][CQ * 2 + j] = c;
        }
}

__global__ __launch_bounds__(512, 2) void gemm256(
    const bf16* __restrict__ A, const bf16* __restrict__ Bt, void* __restrict__ C,
    int Ntot, int Ktot, int outf32, int ropeflag, const float2* __restrict__ cs) {
    __shared__ bf16 lds[2][2][2][128 * 64];   // [buf][A/B][half] = 128 KiB
    const int tid = threadIdx.x;
    const int w = tid >> 6, lane = tid & 63;
    const int quad = lane >> 4, l16 = lane & 15;
    const int wr = w >> 2, wc = w & 3;

    // XCD-aware bijective swizzle (T1)
    const int gx = gridDim.x;
    const int nwg = gx * gridDim.y;
    int orig = blockIdx.y * gx + blockIdx.x;
    int q8 = nwg >> 3, r8 = nwg & 7;
    int xcd = orig & 7, lid = orig >> 3;
    int wg = (xcd < r8 ? xcd * (q8 + 1) : r8 * (q8 + 1) + (xcd - r8) * q8) + lid;
    const long m0 = (long)(wg / gx) << 8;
    const long n0 = (long)(wg % gx) << 8;

    const long rowK = Ktot;
    const int srow = w * 16 + (lane >> 3);
    const int scol = ((lane & 7) ^ (lane >> 3)) << 3;
    const bf16* baseA = A  + (m0 + srow) * rowK + scol;
    const bf16* baseB = Bt + (n0 + srow) * rowK + scol;
    const int d0 = w * 1024 + lane * 8;

    const int m7 = l16 & 7;
    const int col0 = ((0 + quad) ^ m7) << 3;
    const int col1 = ((4 + quad) ^ m7) << 3;
    const int brow = (wc & 1) * 64;

    floatx4 acc[8][4];
#pragma unroll
    for (int i = 0; i < 8; ++i)
#pragma unroll
        for (int j = 0; j < 4; ++j)
#pragma unroll
            for (int r = 0; r < 4; ++r) acc[i][j][r] = 0.f;

    bf16x8 af[4][2], bq0[2][2], bq1[2][2];

    const int T = Ktot >> 6;
    stage_half(baseA,                   &lds[0][0][0][d0], rowK);
    stage_half(baseA + 128 * rowK,      &lds[0][0][1][d0], rowK);
    stage_half(baseB,                   &lds[0][1][0][d0], rowK);
    stage_half(baseB + 128 * rowK,      &lds[0][1][1][d0], rowK);
    stage_half(baseB + 64,              &lds[1][1][0][d0], rowK);
    stage_half(baseB + 128 * rowK + 64, &lds[1][1][1][d0], rowK);
    asm volatile("s_waitcnt vmcnt(4)" ::: "memory");
    barrier_();

    for (int t = 0; t < T; ++t) {
        const int cur = t & 1, nxt = cur ^ 1;
        const bf16* pa = &lds[cur][0][wr][0];
        const bf16* pb = &lds[cur][1][wc >> 1][0];
        const long koff  = (long)(t + 1) * 64;
        const long koff2 = (long)(t + 2) * 64;

        // p1: A q0 + B q0 | stage (t+1).A0
        lda_g<0, 64>(pa, l16, col0, col1, af);
        ldb_g<0>(pb, brow, l16, col0, col1, bq0);
        if (t + 1 < T) stage_half(baseA + koff, &lds[nxt][0][0][d0], rowK);
        barrier_();
        asm volatile("s_waitcnt lgkmcnt(0)" ::: "memory");
        __builtin_amdgcn_sched_barrier(0);
        __builtin_amdgcn_s_setprio(1);
        mma8<0, 0>(af, bq0, acc);
        __builtin_amdgcn_s_setprio(0);
        barrier_();

        // p2: B q1 | stage (t+1).A1
        ldb_g<1>(pb, brow, l16, col0, col1, bq1);
        if (t + 1 < T) stage_half(baseA + 128 * rowK + koff, &lds[nxt][0][1][d0], rowK);
        barrier_();
        asm volatile("s_waitcnt lgkmcnt(0)" ::: "memory");
        __builtin_amdgcn_sched_barrier(0);
        __builtin_amdgcn_s_setprio(1);
        mma8<0, 1>(af, bq1, acc);
        __builtin_amdgcn_s_setprio(0);
        barrier_();

        // p3: A q1 | stage (t+2).B0
        lda_g<1, 64>(pa, l16, col0, col1, af);
        if (t + 2 < T) stage_half(baseB + koff2, &lds[cur][1][0][d0], rowK);
        barrier_();
        asm volatile("s_waitcnt lgkmcnt(0)" ::: "memory");
        __builtin_amdgcn_sched_barrier(0);
        __builtin_amdgcn_s_setprio(1);
        mma8<1, 0>(af, bq0, acc);
        __builtin_amdgcn_s_setprio(0);
        barrier_();

        // p4: stage (t+2).B1 | counted vmcnt
        if (t + 2 < T) stage_half(baseB + 128 * rowK + koff2, &lds[cur][1][1][d0], rowK);
        barrier_();
        asm volatile("s_waitcnt lgkmcnt(0)" ::: "memory");
        __builtin_amdgcn_sched_barrier(0);
        __builtin_amdgcn_s_setprio(1);
        mma8<1, 1>(af, bq1, acc);
        __builtin_amdgcn_s_setprio(0);
        if (t + 2 < T) asm volatile("s_waitcnt vmcnt(4)" ::: "memory");
        else           asm volatile("s_waitcnt vmcnt(0)" ::: "memory");
        barrier_();
    }

    // epilogue: row = quad*4 + r, col = l16; optional fused RoPE
    const int dorope = ropeflag && (n0 < 2560);
    const float sgn = (lane & 1) ? 1.f : -1.f;
#pragma unroll
    for (int ri = 0; ri < 8; ++ri)
#pragma unroll
        for (int j = 0; j < 4; ++j)
#pragma unroll
            for (int r = 0; r < 4; ++r) {
                long m = m0 + wr * 128 + ri * 16 + quad * 4 + r;
                long n = n0 + wc * 64 + j * 16 + l16;
                float v = acc[ri][j][r];
                if (dorope) {
                    int l = (int)(m % L_);
                    float2 csv = cs[l * 32 + ((int)(n >> 1) & 31)];
                    float p = __shfl_xor(v, 1);
                    v = v * csv.x + p * sgn * csv.y;
                }
                if (outf32) ((float*)C)[m * Ntot + n] = v;
                else        ((bf16*)C)[m * Ntot + n] = (bf16)v;
            }
}

// ===========================================================================
// 256x128 GEMM for the wo projection (fill: 16x14 = 224 blocks).
// 8 waves (4Mx2N), wave tile 64x64, BK=64. A double-buffered (2x2 halves),
// B tri-buffered (3 slots) so B(t+2) staging never targets a slot in use and
// the steady-state wait is vmcnt(2) (never 0). 2 phases/K-tile x 16 MFMA.
// LDS = 64 + 48 = 112 KiB.
// ===========================================================================
template <int CH>
__device__ inline void mma4(const bf16x8 (&af)[4][2], const bf16x8 (&bq)[2][2],
                            floatx4 (&acc)[4][4]) {
#pragma unroll
    for (int i = 0; i < 4; ++i)
#pragma unroll
        for (int j = 0; j < 2; ++j) {
            floatx4 c = acc[i][CH * 2 + j];
            c = __builtin_amdgcn_mfma_f32_16x16x32_bf16(af[i][0], bq[j][0], c, 0, 0, 0);
            c = __builtin_amdgcn_mfma_f32_16x16x32_bf16(af[i][1], bq[j][1], c, 0, 0, 0);
            acc[i][CH * 2 + j] = c;
        }
}

__global__ __launch_bounds__(512, 2) void gemm256x128(
    const bf16* __restrict__ A, const bf16* __restrict__ Bt, float* __restrict__ C,
    int Ntot, int Ktot) {
    __shared__ bf16 ldsA[2][2][128 * 64];   // 64 KiB
    __shared__ bf16 ldsB[3][128 * 64];      // 48 KiB
    const int tid = threadIdx.x;
    const int w = tid >> 6, lane = tid & 63;
    const int quad = lane >> 4, l16 = lane & 15;
    const int wr = w >> 1, wc = w & 1;

    const int gx = gridDim.x;
    const int nwg = gx * gridDim.y;
    int orig = blockIdx.y * gx + blockIdx.x;
    int q8 = nwg >> 3, r8 = nwg & 7;
    int xcd = orig & 7, lid = orig >> 3;
    int wg = (xcd < r8 ? xcd * (q8 + 1) : r8 * (q8 + 1) + (xcd - r8) * q8) + lid;
    const long m0 = (long)(wg / gx) << 8;
    const long n0 = (long)(wg % gx) << 7;

    const long rowK = Ktot;
    const int srow = w * 16 + (lane >> 3);
    const int scol = ((lane & 7) ^ (lane >> 3)) << 3;
    const bf16* baseA = A  + (m0 + srow) * rowK + scol;
    const bf16* baseB = Bt + (n0 + srow) * rowK + scol;
    const int d0 = w * 1024 + lane * 8;

    const int m7 = l16 & 7;
    const int col0 = ((0 + quad) ^ m7) << 3;
    const int col1 = ((4 + quad) ^ m7) << 3;
    const int arow = (wr & 1) * 64;   // row base within A-half
    const int brow = wc * 64;         // row base within B slot

    floatx4 acc[4][4];
#pragma unroll
    for (int i = 0; i < 4; ++i)
#pragma unroll
        for (int j = 0; j < 4; ++j)
#pragma unroll
            for (int r = 0; r < 4; ++r) acc[i][j][r] = 0.f;

    bf16x8 af[4][2], bq0[2][2], bq1[2][2];

    const int T = Ktot >> 6;
    // prologue: A(0) both halves -> buf0; B(0) -> slot0; B(1) -> slot1
    stage_half(baseA,              &ldsA[0][0][d0], rowK);
    stage_half(baseA + 128 * rowK, &ldsA[0][1][d0], rowK);
    stage_half(baseB,              &ldsB[0][d0],    rowK);
    stage_half(baseB + 64,         &ldsB[1][d0],    rowK);
    asm volatile("s_waitcnt vmcnt(2)" ::: "memory");   // A(0), B(0) landed
    barrier_();

    int bs = 0;   // B slot of tile t
    for (int t = 0; t < T; ++t) {
        const int cur = t & 1, nxt = cur ^ 1;
        const bf16* pa = &ldsA[cur][wr >> 1][0];
        const bf16* pb = &ldsB[bs][0];
        const long koff  = (long)(t + 1) * 64;
        const long koff2 = (long)(t + 2) * 64;
        const int bs2 = bs >= 1 ? bs - 1 : 2;   // (t+2) % 3

        // p1: A all + B j0,j1 | stage (t+1).A (both halves -> nxt)
        lda_g<0, 0>(pa, arow + l16, col0, col1, af);   // rows arow + i*16 + l16
        ldb_g<0>(pb, brow, l16, col0, col1, bq0);
        if (t + 1 < T) {
            stage_half(baseA + koff,              &ldsA[nxt][0][d0], rowK);
            stage_half(baseA + 128 * rowK + koff, &ldsA[nxt][1][d0], rowK);
        }
        barrier_();
        asm volatile("s_waitcnt lgkmcnt(0)" ::: "memory");
        __builtin_amdgcn_sched_barrier(0);
        __builtin_amdgcn_s_setprio(1);
        mma4<0>(af, bq0, acc);
        __builtin_amdgcn_s_setprio(0);
        barrier_();

        // p2: B j2,j3 | stage (t+2).B -> slot bs2 | counted vmcnt
        ldb_g<1>(pb, brow, l16, col0, col1, bq1);
        if (t + 2 < T) stage_half(baseB + koff2, &ldsB[bs2][d0], rowK);
        barrier_();
        asm volatile("s_waitcnt lgkmcnt(0)" ::: "memory");
        __builtin_amdgcn_sched_barrier(0);
        __builtin_amdgcn_s_setprio(1);
        mma4<1>(af, bq1, acc);
        __builtin_amdgcn_s_setprio(0);
        if      (t + 2 < T) asm volatile("s_waitcnt vmcnt(2)" ::: "memory");
        else if (t + 1 < T) asm volatile("s_waitcnt vmcnt(0)" ::: "memory");
        barrier_();
        bs = bs < 2 ? bs + 1 : 0;
    }

    // epilogue: row = quad*4 + r, col = l16; fp32 out
#pragma unroll
    for (int i = 0; i < 4; ++i)
#pragma unroll
        for (int j = 0; j < 4; ++j)
#pragma unroll
            for (int r = 0; r < 4; ++r) {
                long m = m0 + wr * 64 + i * 16 + quad * 4 + r;
                long n = n0 + wc * 64 + j * 16 + l16;
                C[m * Ntot + n] = acc[i][j][r];
            }
}

// ---------------------------------------------------------------------------
// Flash attention v3 (unchanged this round).
// ---------------------------------------------------------------------------
__global__ __launch_bounds__(256) void attn_kernel(
    const bf16* __restrict__ QKV,  // [M][3072]: q(rope'd) | k(rope'd) | v
    const bf16* __restrict__ Vt,   // [B][HKV][64][896]
    bf16* __restrict__ AO) {       // [M][2048]
    __shared__ bf16 Ks[64 * 72];
    __shared__ bf16 Vs[64 * 72];
    __shared__ bf16 Ps[4][16 * 72];
    const int tid  = threadIdx.x;
    const int wid  = tid >> 6, lane = tid & 63;
    const int quad = lane >> 4, c = lane & 15;
    const int b = blockIdx.z, hq = blockIdx.y, kvh = hq >> 2;
    const int q0b = blockIdx.x * 64;
    const int q0 = q0b + wid * 16;
    bf16* ps = &Ps[wid][0];

    const bf16* Qb = QKV + ((long)(b * L_ + q0)) * NQKV + hq * HD_;
    const bf16* Kb = QKV + ((long)(b * L_)) * NQKV + D_ + kvh * HD_;
    const bf16* Vb = Vt + ((long)(b * HKV_ + kvh)) * (HD_ * L_);

    bf16x8 qf0 = *(const bf16x8*)&Qb[(long)c * NQKV + quad * 8];
    bf16x8 qf1 = *(const bf16x8*)&Qb[(long)c * NQKV + 32 + quad * 8];

    float lsum[4];
    floatx4 o[4];
#pragma unroll
    for (int r = 0; r < 4; r++) lsum[r] = 0.f;
#pragma unroll
    for (int nt = 0; nt < 4; nt++)
#pragma unroll
        for (int r = 0; r < 4; r++) o[nt][r] = 0.f;

    int fe[4];
#pragma unroll
    for (int r = 0; r < 4; r++) { int l = q0 + quad * 4 + r; fe[r] = (l / 7 + 1) * 7; }
    const int kend = ((q0b + 63) / 7 + 1) * 7;

    const int srow = tid >> 3, schunk = (tid & 7) << 3;

    for (int k0 = 0; k0 < kend; k0 += 64) {
        bf16x8 kg0 = *(const bf16x8*)&Kb[(long)(k0 + srow) * NQKV + schunk];
        bf16x8 kg1 = *(const bf16x8*)&Kb[(long)(k0 + 32 + srow) * NQKV + schunk];
        bf16x8 vg0 = *(const bf16x8*)&Vb[(long)srow * L_ + k0 + schunk];
        bf16x8 vg1 = *(const bf16x8*)&Vb[(long)(srow + 32) * L_ + k0 + schunk];
        __syncthreads();
        *(bf16x8*)&Ks[srow * 72 + schunk]        = kg0;
        *(bf16x8*)&Ks[(srow + 32) * 72 + schunk] = kg1;
        *(bf16x8*)&Vs[srow * 72 + schunk]        = vg0;
        *(bf16x8*)&Vs[(srow + 32) * 72 + schunk] = vg1;
        __syncthreads();

        floatx4 s[4];
#pragma unroll
        for (int n = 0; n < 4; n++) {
#pragma unroll
            for (int r = 0; r < 4; r++) s[n][r] = 0.f;
            bf16x8 kf0 = *(bf16x8*)&Ks[(n * 16 + c) * 72 + quad * 8];
            bf16x8 kf1 = *(bf16x8*)&Ks[(n * 16 + c) * 72 + 32 + quad * 8];
            s[n] = __builtin_amdgcn_mfma_f32_16x16x32_bf16(qf0, kf0, s[n], 0, 0, 0);
            s[n] = __builtin_amdgcn_mfma_f32_16x16x32_bf16(qf1, kf1, s[n], 0, 0, 0);
        }
#pragma unroll
        for (int n = 0; n < 4; n++) {
            const int key = k0 + n * 16 + c;
#pragma unroll
            for (int r = 0; r < 4; r++) {
                float e = __expf(fmaf(s[n][r], 0.125f, -12.0f));
                e = (key < fe[r]) ? e : 0.f;
                lsum[r] += e;
                ps[(quad * 4 + r) * 72 + n * 16 + c] = (bf16)e;
            }
        }
        bf16x8 pf0 = *(bf16x8*)&ps[c * 72 + quad * 8];
        bf16x8 pf1 = *(bf16x8*)&ps[c * 72 + 32 + quad * 8];
#pragma unroll
        for (int nt = 0; nt < 4; nt++) {
            bf16x8 vf0 = *(bf16x8*)&Vs[(nt * 16 + c) * 72 + quad * 8];
            bf16x8 vf1 = *(bf16x8*)&Vs[(nt * 16 + c) * 72 + 32 + quad * 8];
            o[nt] = __builtin_amdgcn_mfma_f32_16x16x32_bf16(pf0, vf0, o[nt], 0, 0, 0);
            o[nt] = __builtin_amdgcn_mfma_f32_16x16x32_bf16(pf1, vf1, o[nt], 0, 0, 0);
        }
    }
#pragma unroll
    for (int r = 0; r < 4; r++) {
#pragma unroll
        for (int off = 1; off < 16; off <<= 1) lsum[r] += __shfl_xor(lsum[r], off);
    }
#pragma unroll
    for (int nt = 0; nt < 4; nt++)
#pragma unroll
        for (int r = 0; r < 4; r++) {
            int l = q0 + quad * 4 + r;
            AO[((long)(b * L_ + l)) * D_ + hq * HD_ + nt * 16 + c] = (bf16)(o[nt][r] / lsum[r]);
        }
}

// ---------------------------------------------------------------------------
extern "C" void kernel_launch(void* const* d_in, const int* in_sizes, int n_in,
                              void* d_out, int out_size, void* d_ws, size_t ws_size,
                              hipStream_t stream) {
    (void)in_sizes; (void)n_in; (void)out_size; (void)ws_size;
    const float* x  = (const float*)d_in[0];
    const float* wq = (const float*)d_in[1];
    const float* wk = (const float*)d_in[2];
    const float* wv = (const float*)d_in[3];
    const float* wo = (const float*)d_in[4];
    const int* pos  = (const int*)d_in[5];

    bf16* ws    = (bf16*)d_ws;
    bf16* xb    = ws;                   // [3584][2048] bf16 x  (reused as AO)
    bf16* wqkvT = ws + 7340032L;        // [3072][2048]  (wq^T | wk^T | wv^T)
    bf16* woT   = ws + 13631488L;       // [2048][2048]
    bf16* QKV   = ws + 17825792L;       // [3584][3072]
    bf16* Vt    = ws + 28835840L;       // [4][8][64][896]
    bf16* AO    = xb;
    float2* cs  = (float2*)(ws + 30670848L);  // [896][32]

    convert_to_bf16<<<dim3(7168), 256, 0, stream>>>(x, xb);
    rope_cs_kernel<<<dim3(112), dim3(256), 0, stream>>>(pos, cs);

    transpose_cvt<<<dim3(32, 32), 256, 0, stream>>>(wq, (ushort*)wqkvT, 2048, 2048);
    transpose_cvt<<<dim3(8, 32), 256, 0, stream>>>(wk, (ushort*)(wqkvT + 4194304L), 512, 2048);
    transpose_cvt<<<dim3(8, 32), 256, 0, stream>>>(wv, (ushort*)(wqkvT + 5242880L), 512, 2048);
    transpose_cvt<<<dim3(32, 32), 256, 0, stream>>>(wo, (ushort*)woT, 2048, 2048);

    // QKV projection + fused RoPE: [3584][2048] x [3072][2048]^T -> bf16
    gemm256<<<dim3(12, 14), 512, 0, stream>>>(xb, wqkvT, QKV, NQKV, D_, 0, 1, cs);

    // V cols of QKV -> Vt[b][h][64][896]
    transpose_u16<<<dim3(1, 14, 32), 256, 0, stream>>>(
        (const ushort*)(QKV + 2560), (ushort*)Vt, 3072, 896,
        896L * 3072, 64, 8L * 57344, 57344);

    attn_kernel<<<dim3(14, 32, 4), 256, 0, stream>>>(QKV, Vt, AO);

    // output projection: [3584][2048] x [2048][2048]^T -> [3584][2048] fp32
    gemm256x128<<<dim3(16, 14), 512, 0, stream>>>(AO, woT, (float*)d_out, D_, D_);
}

// Round 5
// 285.890 us; speedup vs baseline: 1.0735x; 1.0735x over previous
//
#include <hip/hip_runtime.h>
#include <hip/hip_bf16.h>
#include <cstdint>

typedef __bf16 bf16;
typedef __bf16 bf16x8 __attribute__((ext_vector_type(8)));
typedef float floatx4 __attribute__((ext_vector_type(4)));

#define B_   4
#define L_   896
#define D_   2048
#define HQ_  32
#define HKV_ 8
#define HD_  64
#define NQKV 3072   /* 2048 q + 512 k + 512 v */
#define M_   3584   /* B_*L_ */

// async global->LDS, 16B per lane. LDS dst must be wave-uniform base + lane*16.
__device__ inline void gl_lds16(const bf16* g, bf16* l) {
    __builtin_amdgcn_global_load_lds(
        (const __attribute__((address_space(1))) void*)g,
        (__attribute__((address_space(3))) void*)l, 16, 0, 0);
}

__device__ inline void barrier_() {
    asm volatile("" ::: "memory");
    __builtin_amdgcn_s_barrier();
    asm volatile("" ::: "memory");
}

// ---------------------------------------------------------------------------
// fp32 -> bf16 (x only). Grid: n/1024 blocks.
// ---------------------------------------------------------------------------
__global__ __launch_bounds__(256) void convert_to_bf16(const float* __restrict__ in,
                                                       bf16* __restrict__ out) {
    long q = (long)blockIdx.x * 256 + threadIdx.x;
    float4 v = ((const float4*)in)[q];
    union { bf16 b[4]; ushort4 u; } w;
    w.b[0] = (bf16)v.x; w.b[1] = (bf16)v.y; w.b[2] = (bf16)v.z; w.b[3] = (bf16)v.w;
    ((ushort4*)out)[q] = w.u;
}

// ---------------------------------------------------------------------------
// RoPE cos/sin table: [L][32] float2
// ---------------------------------------------------------------------------
__global__ __launch_bounds__(256) void rope_cs_kernel(const int* __restrict__ pos_ids,
                                                      float2* __restrict__ cs) {
    int idx = blockIdx.x * 256 + threadIdx.x;
    if (idx >= L_ * 32) return;
    int l = idx >> 5, i = idx & 31;
    float p = (float)pos_ids[l];
    float inv = exp2f(-(float)i * (13.287712379549449f / 32.0f));  // 10000^(-i/32)
    float a = p * inv;
    cs[idx] = make_float2(cosf(a), sinf(a));
}

// ---------------------------------------------------------------------------
// Standalone RoPE, vectorized: 4 pairs (16 B) per thread, in place on
// QKV cols [0,2560). Grid: 3584*320/256 = 4480 blocks.
// ---------------------------------------------------------------------------
__global__ __launch_bounds__(256) void rope_apply(bf16* __restrict__ QKV,
                                                  const float2* __restrict__ cs) {
    int idx = blockIdx.x * 256 + threadIdx.x;   // [0, 3584*320)
    int m = idx / 320, g = idx - m * 320;       // 4-pair group; cols 8g..8g+7
    int l = m % L_;
    int hp = (g * 4) & 31;                      // head-local pair idx of pair0
    const float2* ct = &cs[l * 32 + hp];
    bf16* p = QKV + (long)m * NQKV + g * 8;
    bf16x8 v = *(bf16x8*)p;
    bf16x8 w;
#pragma unroll
    for (int i = 0; i < 4; i++) {
        float2 csv = ct[i];
        float x1 = (float)v[2 * i], x2 = (float)v[2 * i + 1];
        w[2 * i]     = (bf16)(x1 * csv.x - x2 * csv.y);
        w[2 * i + 1] = (bf16)(x1 * csv.y + x2 * csv.x);
    }
    *(bf16x8*)p = w;
}

// ---------------------------------------------------------------------------
// Fused fp32->bf16 + 64x64 tiled transpose. in fp32 [R][C] -> out bf16 [C][R].
// ---------------------------------------------------------------------------
__global__ __launch_bounds__(256) void transpose_cvt(
    const float* __restrict__ in, ushort* __restrict__ out, int C, int R) {
    __shared__ ushort t[64][72];
    int tid = threadIdx.x;
    int tr = tid >> 4, tc = (tid & 15) << 2;
    long r0 = (long)blockIdx.y << 6, c0 = (long)blockIdx.x << 6;
#pragma unroll
    for (int i = 0; i < 4; ++i) {
        float4 v = *(const float4*)&in[(r0 + tr + i * 16) * C + c0 + tc];
        union { bf16 b[4]; ushort4 u; } w;
        w.b[0] = (bf16)v.x; w.b[1] = (bf16)v.y; w.b[2] = (bf16)v.z; w.b[3] = (bf16)v.w;
        *(ushort4*)&t[tr + i * 16][tc] = w.u;
    }
    __syncthreads();
#pragma unroll
    for (int i = 0; i < 4; ++i) {
        ushort4 w;
        w.x = t[tc + 0][tr + i * 16];
        w.y = t[tc + 1][tr + i * 16];
        w.z = t[tc + 2][tr + i * 16];
        w.w = t[tc + 3][tr + i * 16];
        *(ushort4*)&out[(c0 + tr + i * 16) * R + r0 + tc] = w;
    }
}

// ---------------------------------------------------------------------------
// bf16 64x64 tiled transpose (for V -> Vt). z-batch as before.
// ---------------------------------------------------------------------------
__global__ __launch_bounds__(256) void transpose_u16(
    const ushort* __restrict__ in, ushort* __restrict__ out,
    int ld_in, int ld_out, long is1, long is2, long os1, long os2) {
    __shared__ ushort t[64][72];
    int z = blockIdx.z;
    const ushort* ip = in + (long)(z >> 3) * is1 + (long)(z & 7) * is2;
    ushort* op = out + (long)(z >> 3) * os1 + (long)(z & 7) * os2;
    int tid = threadIdx.x;
    int tr = tid >> 4, tc = (tid & 15) << 2;
    long r0 = (long)blockIdx.y << 6, c0 = (long)blockIdx.x << 6;
#pragma unroll
    for (int i = 0; i < 4; ++i) {
        ushort4 v = *(const ushort4*)&ip[(r0 + tr + i * 16) * ld_in + c0 + tc];
        *(ushort4*)&t[tr + i * 16][tc] = v;
    }
    __syncthreads();
#pragma unroll
    for (int i = 0; i < 4; ++i) {
        ushort4 w;
        w.x = t[tc + 0][tr + i * 16];
        w.y = t[tc + 1][tr + i * 16];
        w.z = t[tc + 2][tr + i * 16];
        w.w = t[tc + 3][tr + i * 16];
        *(ushort4*)&op[(c0 + tr + i * 16) * ld_out + r0 + tc] = w;
    }
}

// ===========================================================================
// Shared GEMM helpers (3-bit slot-swizzled [128][64] bf16 LDS halves).
// Swizzle: a row is 8 x 16B slots; phys_slot = log_slot ^ (row & 7).
// Staging (rule #21): gl_lds writes linearly; lane l of wave w sources global
//   (row = 16w + (l>>3), col = ((l&7)^(l>>3))<<3); chunks +8 rows (0 mod 8).
// Read: fragment (row, ks*32+quad*8) -> col = ((ks*4+quad)^(row&7))<<3.
// ===========================================================================

template <int RQ, int RESPAN>
__device__ inline void lda_g(const bf16* p, int l16, int c0, int c1, bf16x8 (&af)[4][2]) {
#pragma unroll
    for (int i = 0; i < 4; ++i) {
        const bf16* rp = &p[(RQ * RESPAN + i * 16 + l16) * 64];
        af[i][0] = *(const bf16x8*)&rp[c0];
        af[i][1] = *(const bf16x8*)&rp[c1];
    }
}

template <int CQ>
__device__ inline void ldb_g(const bf16* p, int brow, int l16, int c0, int c1,
                             bf16x8 (&bq)[2][2]) {
#pragma unroll
    for (int j = 0; j < 2; ++j) {
        const bf16* rp = &p[(brow + (CQ * 2 + j) * 16 + l16) * 64];
        bq[j][0] = *(const bf16x8*)&rp[c0];
        bq[j][1] = *(const bf16x8*)&rp[c1];
    }
}

__device__ inline void stage_half(const bf16* gsrc, bf16* ldst, long rowK) {
    gl_lds16(gsrc,            ldst);
    gl_lds16(gsrc + 8 * rowK, ldst + 512);
}

// ===========================================================================
// 256x256 8-phase GEMM (m201-style): C[M][N] = A[M][K] * Bt[N][K]^T.
// 8 waves (2Mx4N), BK=64, 128 KiB dbuf LDS, counted vmcnt, setprio.
// (RoPE fusion REVERTED: the scattered-cs epilogue was latency-serialized,
//  +33 us at 1 block/CU. rope_apply standalone is ~12 us.)
// ===========================================================================
template <int RQ, int CQ>
__device__ inline void mma8(const bf16x8 (&af)[4][2], const bf16x8 (&bq)[2][2],
                            floatx4 (&acc)[8][4]) {
#pragma unroll
    for (int i = 0; i < 4; ++i)
#pragma unroll
        for (int j = 0; j < 2; ++j) {
            floatx4 c = acc[RQ * 4 + i][CQ * 2 + j];
            c = __builtin_amdgcn_mfma_f32_16x16x32_bf16(af[i][0], bq[j][0], c, 0, 0, 0);
            c = __builtin_amdgcn_mfma_f32_16x16x32_bf16(af[i][1], bq[j][1], c, 0, 0, 0);
            acc[RQ * 4 + i][CQ * 2 + j] = c;
        }
}

__global__ __launch_bounds__(512, 2) void gemm256(
    const bf16* __restrict__ A, const bf16* __restrict__ Bt, void* __restrict__ C,
    int Ntot, int Ktot, int outf32) {
    __shared__ bf16 lds[2][2][2][128 * 64];   // [buf][A/B][half] = 128 KiB
    const int tid = threadIdx.x;
    const int w = tid >> 6, lane = tid & 63;
    const int quad = lane >> 4, l16 = lane & 15;
    const int wr = w >> 2, wc = w & 3;

    // XCD-aware bijective swizzle (T1)
    const int gx = gridDim.x;
    const int nwg = gx * gridDim.y;
    int orig = blockIdx.y * gx + blockIdx.x;
    int q8 = nwg >> 3, r8 = nwg & 7;
    int xcd = orig & 7, lid = orig >> 3;
    int wg = (xcd < r8 ? xcd * (q8 + 1) : r8 * (q8 + 1) + (xcd - r8) * q8) + lid;
    const long m0 = (long)(wg / gx) << 8;
    const long n0 = (long)(wg % gx) << 8;

    const long rowK = Ktot;
    const int srow = w * 16 + (lane >> 3);
    const int scol = ((lane & 7) ^ (lane >> 3)) << 3;
    const bf16* baseA = A  + (m0 + srow) * rowK + scol;
    const bf16* baseB = Bt + (n0 + srow) * rowK + scol;
    const int d0 = w * 1024 + lane * 8;

    const int m7 = l16 & 7;
    const int col0 = ((0 + quad) ^ m7) << 3;
    const int col1 = ((4 + quad) ^ m7) << 3;
    const int brow = (wc & 1) * 64;

    floatx4 acc[8][4];
#pragma unroll
    for (int i = 0; i < 8; ++i)
#pragma unroll
        for (int j = 0; j < 4; ++j)
#pragma unroll
            for (int r = 0; r < 4; ++r) acc[i][j][r] = 0.f;

    bf16x8 af[4][2], bq0[2][2], bq1[2][2];

    const int T = Ktot >> 6;
    stage_half(baseA,                   &lds[0][0][0][d0], rowK);
    stage_half(baseA + 128 * rowK,      &lds[0][0][1][d0], rowK);
    stage_half(baseB,                   &lds[0][1][0][d0], rowK);
    stage_half(baseB + 128 * rowK,      &lds[0][1][1][d0], rowK);
    stage_half(baseB + 64,              &lds[1][1][0][d0], rowK);
    stage_half(baseB + 128 * rowK + 64, &lds[1][1][1][d0], rowK);
    asm volatile("s_waitcnt vmcnt(4)" ::: "memory");
    barrier_();

    for (int t = 0; t < T; ++t) {
        const int cur = t & 1, nxt = cur ^ 1;
        const bf16* pa = &lds[cur][0][wr][0];
        const bf16* pb = &lds[cur][1][wc >> 1][0];
        const long koff  = (long)(t + 1) * 64;
        const long koff2 = (long)(t + 2) * 64;

        // p1: A q0 + B q0 | stage (t+1).A0
        lda_g<0, 64>(pa, l16, col0, col1, af);
        ldb_g<0>(pb, brow, l16, col0, col1, bq0);
        if (t + 1 < T) stage_half(baseA + koff, &lds[nxt][0][0][d0], rowK);
        barrier_();
        asm volatile("s_waitcnt lgkmcnt(0)" ::: "memory");
        __builtin_amdgcn_sched_barrier(0);
        __builtin_amdgcn_s_setprio(1);
        mma8<0, 0>(af, bq0, acc);
        __builtin_amdgcn_s_setprio(0);
        barrier_();

        // p2: B q1 | stage (t+1).A1
        ldb_g<1>(pb, brow, l16, col0, col1, bq1);
        if (t + 1 < T) stage_half(baseA + 128 * rowK + koff, &lds[nxt][0][1][d0], rowK);
        barrier_();
        asm volatile("s_waitcnt lgkmcnt(0)" ::: "memory");
        __builtin_amdgcn_sched_barrier(0);
        __builtin_amdgcn_s_setprio(1);
        mma8<0, 1>(af, bq1, acc);
        __builtin_amdgcn_s_setprio(0);
        barrier_();

        // p3: A q1 | stage (t+2).B0
        lda_g<1, 64>(pa, l16, col0, col1, af);
        if (t + 2 < T) stage_half(baseB + koff2, &lds[cur][1][0][d0], rowK);
        barrier_();
        asm volatile("s_waitcnt lgkmcnt(0)" ::: "memory");
        __builtin_amdgcn_sched_barrier(0);
        __builtin_amdgcn_s_setprio(1);
        mma8<1, 0>(af, bq0, acc);
        __builtin_amdgcn_s_setprio(0);
        barrier_();

        // p4: stage (t+2).B1 | counted vmcnt
        if (t + 2 < T) stage_half(baseB + 128 * rowK + koff2, &lds[cur][1][1][d0], rowK);
        barrier_();
        asm volatile("s_waitcnt lgkmcnt(0)" ::: "memory");
        __builtin_amdgcn_sched_barrier(0);
        __builtin_amdgcn_s_setprio(1);
        mma8<1, 1>(af, bq1, acc);
        __builtin_amdgcn_s_setprio(0);
        if (t + 2 < T) asm volatile("s_waitcnt vmcnt(4)" ::: "memory");
        else           asm volatile("s_waitcnt vmcnt(0)" ::: "memory");
        barrier_();
    }

    // epilogue: row = quad*4 + r, col = l16
#pragma unroll
    for (int ri = 0; ri < 8; ++ri)
#pragma unroll
        for (int j = 0; j < 4; ++j)
#pragma unroll
            for (int r = 0; r < 4; ++r) {
                long m = m0 + wr * 128 + ri * 16 + quad * 4 + r;
                long n = n0 + wc * 64 + j * 16 + l16;
                if (outf32) ((float*)C)[m * Ntot + n] = acc[ri][j][r];
                else        ((bf16*)C)[m * Ntot + n] = (bf16)acc[ri][j][r];
            }
}

// ===========================================================================
// 256x128 GEMM for the wo projection (fill: 16x14 = 224 blocks).
// 8 waves (4Mx2N), wave tile 64x64, BK=64. A double-buffered (2x2 halves),
// B tri-buffered (3 slots); steady-state wait vmcnt(2). LDS = 112 KiB.
// ===========================================================================
template <int CH>
__device__ inline void mma4(const bf16x8 (&af)[4][2], const bf16x8 (&bq)[2][2],
                            floatx4 (&acc)[4][4]) {
#pragma unroll
    for (int i = 0; i < 4; ++i)
#pragma unroll
        for (int j = 0; j < 2; ++j) {
            floatx4 c = acc[i][CH * 2 + j];
            c = __builtin_amdgcn_mfma_f32_16x16x32_bf16(af[i][0], bq[j][0], c, 0, 0, 0);
            c = __builtin_amdgcn_mfma_f32_16x16x32_bf16(af[i][1], bq[j][1], c, 0, 0, 0);
            acc[i][CH * 2 + j] = c;
        }
}

__global__ __launch_bounds__(512, 2) void gemm256x128(
    const bf16* __restrict__ A, const bf16* __restrict__ Bt, float* __restrict__ C,
    int Ntot, int Ktot) {
    __shared__ bf16 ldsA[2][2][128 * 64];   // 64 KiB
    __shared__ bf16 ldsB[3][128 * 64];      // 48 KiB
    const int tid = threadIdx.x;
    const int w = tid >> 6, lane = tid & 63;
    const int quad = lane >> 4, l16 = lane & 15;
    const int wr = w >> 1, wc = w & 1;

    const int gx = gridDim.x;
    const int nwg = gx * gridDim.y;
    int orig = blockIdx.y * gx + blockIdx.x;
    int q8 = nwg >> 3, r8 = nwg & 7;
    int xcd = orig & 7, lid = orig >> 3;
    int wg = (xcd < r8 ? xcd * (q8 + 1) : r8 * (q8 + 1) + (xcd - r8) * q8) + lid;
    const long m0 = (long)(wg / gx) << 8;
    const long n0 = (long)(wg % gx) << 7;

    const long rowK = Ktot;
    const int srow = w * 16 + (lane >> 3);
    const int scol = ((lane & 7) ^ (lane >> 3)) << 3;
    const bf16* baseA = A  + (m0 + srow) * rowK + scol;
    const bf16* baseB = Bt + (n0 + srow) * rowK + scol;
    const int d0 = w * 1024 + lane * 8;

    const int m7 = l16 & 7;
    const int col0 = ((0 + quad) ^ m7) << 3;
    const int col1 = ((4 + quad) ^ m7) << 3;
    const int arow = (wr & 1) * 64;   // row base within A-half
    const int brow = wc * 64;         // row base within B slot

    floatx4 acc[4][4];
#pragma unroll
    for (int i = 0; i < 4; ++i)
#pragma unroll
        for (int j = 0; j < 4; ++j)
#pragma unroll
            for (int r = 0; r < 4; ++r) acc[i][j][r] = 0.f;

    bf16x8 af[4][2], bq0[2][2], bq1[2][2];

    const int T = Ktot >> 6;
    stage_half(baseA,              &ldsA[0][0][d0], rowK);
    stage_half(baseA + 128 * rowK, &ldsA[0][1][d0], rowK);
    stage_half(baseB,              &ldsB[0][d0],    rowK);
    stage_half(baseB + 64,         &ldsB[1][d0],    rowK);
    asm volatile("s_waitcnt vmcnt(2)" ::: "memory");   // A(0), B(0) landed
    barrier_();

    int bs = 0;   // B slot of tile t
    for (int t = 0; t < T; ++t) {
        const int cur = t & 1, nxt = cur ^ 1;
        const bf16* pa = &ldsA[cur][wr >> 1][0];
        const bf16* pb = &ldsB[bs][0];
        const long koff  = (long)(t + 1) * 64;
        const long koff2 = (long)(t + 2) * 64;
        const int bs2 = bs >= 1 ? bs - 1 : 2;   // (t+2) % 3

        // p1: A all + B j0,j1 | stage (t+1).A (both halves -> nxt)
        lda_g<0, 0>(pa, arow + l16, col0, col1, af);
        ldb_g<0>(pb, brow, l16, col0, col1, bq0);
        if (t + 1 < T) {
            stage_half(baseA + koff,              &ldsA[nxt][0][d0], rowK);
            stage_half(baseA + 128 * rowK + koff, &ldsA[nxt][1][d0], rowK);
        }
        barrier_();
        asm volatile("s_waitcnt lgkmcnt(0)" ::: "memory");
        __builtin_amdgcn_sched_barrier(0);
        __builtin_amdgcn_s_setprio(1);
        mma4<0>(af, bq0, acc);
        __builtin_amdgcn_s_setprio(0);
        barrier_();

        // p2: B j2,j3 | stage (t+2).B -> slot bs2 | counted vmcnt
        ldb_g<1>(pb, brow, l16, col0, col1, bq1);
        if (t + 2 < T) stage_half(baseB + koff2, &ldsB[bs2][d0], rowK);
        barrier_();
        asm volatile("s_waitcnt lgkmcnt(0)" ::: "memory");
        __builtin_amdgcn_sched_barrier(0);
        __builtin_amdgcn_s_setprio(1);
        mma4<1>(af, bq1, acc);
        __builtin_amdgcn_s_setprio(0);
        if      (t + 2 < T) asm volatile("s_waitcnt vmcnt(2)" ::: "memory");
        else if (t + 1 < T) asm volatile("s_waitcnt vmcnt(0)" ::: "memory");
        barrier_();
        bs = bs < 2 ? bs + 1 : 0;
    }

#pragma unroll
    for (int i = 0; i < 4; ++i)
#pragma unroll
        for (int j = 0; j < 4; ++j)
#pragma unroll
            for (int r = 0; r < 4; ++r) {
                long m = m0 + wr * 64 + i * 16 + quad * 4 + r;
                long n = n0 + wc * 64 + j * 16 + l16;
                C[m * Ntot + n] = acc[i][j][r];
            }
}

// ---------------------------------------------------------------------------
// Flash attention, GQA-group blocking: one block = 4 waves = the 4 q-heads
// sharing one kv-head; all waves share K/V LDS staging (staging+barriers /4).
// Wave w handles head hq = kvh*4 + w over ALL 64 q-rows of the q-tile:
// per 64-key tile, 32 QK MFMA + 32 PV MFMA per wave against 2 barriers.
// K-frags / V-frags hoisted once per tile (4x reuse across row-frags).
// Grid: (14, 8, 4). LDS = Ks + Vs + 4*Ps = 55.3 KB -> 2 blocks/CU.
// Fixed-max softmax: p = exp(s/8 - 12) (scores bounded, no online rescale).
// ---------------------------------------------------------------------------
__global__ __launch_bounds__(256) void attn_kernel(
    const bf16* __restrict__ QKV,  // [M][3072]: q(rope'd) | k(rope'd) | v
    const bf16* __restrict__ Vt,   // [B][HKV][64][896]
    bf16* __restrict__ AO) {       // [M][2048]
    __shared__ bf16 Ks[64 * 72];
    __shared__ bf16 Vs[64 * 72];
    __shared__ bf16 Ps[4][64 * 72];
    const int tid  = threadIdx.x;
    const int wid  = tid >> 6, lane = tid & 63;
    const int quad = lane >> 4, c = lane & 15;
    const int b = blockIdx.z, kvh = blockIdx.y;
    const int hq = kvh * 4 + wid;
    const int q0b = blockIdx.x * 64;
    bf16* ps = &Ps[wid][0];

    const bf16* Qb = QKV + ((long)(b * L_ + q0b)) * NQKV + hq * HD_;
    const bf16* Kb = QKV + ((long)(b * L_)) * NQKV + D_ + kvh * HD_;
    const bf16* Vb = Vt + ((long)(b * HKV_ + kvh)) * (HD_ * L_);

    // Q fragments: 4 row-frags (a) x 2 k-slices, rows a*16 + c
    bf16x8 qf[4][2];
#pragma unroll
    for (int a = 0; a < 4; a++) {
        qf[a][0] = *(const bf16x8*)&Qb[(long)(a * 16 + c) * NQKV + quad * 8];
        qf[a][1] = *(const bf16x8*)&Qb[(long)(a * 16 + c) * NQKV + 32 + quad * 8];
    }

    float lsum[4][4];
    floatx4 o[4][4];
#pragma unroll
    for (int a = 0; a < 4; a++)
#pragma unroll
        for (int r = 0; r < 4; r++) lsum[a][r] = 0.f;
#pragma unroll
    for (int a = 0; a < 4; a++)
#pragma unroll
        for (int nt = 0; nt < 4; nt++)
#pragma unroll
            for (int r = 0; r < 4; r++) o[a][nt][r] = 0.f;

    int fe[4][4];  // exclusive frame-end per row (row = a*16 + quad*4 + r)
#pragma unroll
    for (int a = 0; a < 4; a++)
#pragma unroll
        for (int r = 0; r < 4; r++) {
            int l = q0b + a * 16 + quad * 4 + r;
            fe[a][r] = (l / 7 + 1) * 7;
        }
    const int kend = ((q0b + 63) / 7 + 1) * 7;   // block-max frame end, <= 896

    const int srow = tid >> 3, schunk = (tid & 7) << 3;

    for (int k0 = 0; k0 < kend; k0 += 64) {
        // cooperative staging (identical to verified pattern)
        bf16x8 kg0 = *(const bf16x8*)&Kb[(long)(k0 + srow) * NQKV + schunk];
        bf16x8 kg1 = *(const bf16x8*)&Kb[(long)(k0 + 32 + srow) * NQKV + schunk];
        bf16x8 vg0 = *(const bf16x8*)&Vb[(long)srow * L_ + k0 + schunk];
        bf16x8 vg1 = *(const bf16x8*)&Vb[(long)(srow + 32) * L_ + k0 + schunk];
        __syncthreads();
        *(bf16x8*)&Ks[srow * 72 + schunk]        = kg0;
        *(bf16x8*)&Ks[(srow + 32) * 72 + schunk] = kg1;
        *(bf16x8*)&Vs[srow * 72 + schunk]        = vg0;
        *(bf16x8*)&Vs[(srow + 32) * 72 + schunk] = vg1;
        __syncthreads();

        // hoisted K fragments (reused by all 4 row-frags)
        bf16x8 kf[4][2];
#pragma unroll
        for (int n = 0; n < 4; n++) {
            kf[n][0] = *(bf16x8*)&Ks[(n * 16 + c) * 72 + quad * 8];
            kf[n][1] = *(bf16x8*)&Ks[(n * 16 + c) * 72 + 32 + quad * 8];
        }
        // QK^T + softmax + P write, per row-frag a
#pragma unroll
        for (int a = 0; a < 4; a++) {
            floatx4 s[4];
#pragma unroll
            for (int n = 0; n < 4; n++) {
#pragma unroll
                for (int r = 0; r < 4; r++) s[n][r] = 0.f;
                s[n] = __builtin_amdgcn_mfma_f32_16x16x32_bf16(qf[a][0], kf[n][0], s[n], 0, 0, 0);
                s[n] = __builtin_amdgcn_mfma_f32_16x16x32_bf16(qf[a][1], kf[n][1], s[n], 0, 0, 0);
            }
#pragma unroll
            for (int n = 0; n < 4; n++) {
                const int key = k0 + n * 16 + c;
#pragma unroll
                for (int r = 0; r < 4; r++) {
                    float e = __expf(fmaf(s[n][r], 0.125f, -12.0f));
                    e = (key < fe[a][r]) ? e : 0.f;
                    lsum[a][r] += e;
                    ps[(a * 16 + quad * 4 + r) * 72 + n * 16 + c] = (bf16)e;
                }
            }
        }
        // hoisted V fragments + PV
        bf16x8 vf[4][2];
#pragma unroll
        for (int nt = 0; nt < 4; nt++) {
            vf[nt][0] = *(bf16x8*)&Vs[(nt * 16 + c) * 72 + quad * 8];
            vf[nt][1] = *(bf16x8*)&Vs[(nt * 16 + c) * 72 + 32 + quad * 8];
        }
#pragma unroll
        for (int a = 0; a < 4; a++) {
            bf16x8 pf0 = *(bf16x8*)&ps[(a * 16 + c) * 72 + quad * 8];
            bf16x8 pf1 = *(bf16x8*)&ps[(a * 16 + c) * 72 + 32 + quad * 8];
#pragma unroll
            for (int nt = 0; nt < 4; nt++) {
                o[a][nt] = __builtin_amdgcn_mfma_f32_16x16x32_bf16(pf0, vf[nt][0], o[a][nt], 0, 0, 0);
                o[a][nt] = __builtin_amdgcn_mfma_f32_16x16x32_bf16(pf1, vf[nt][1], o[a][nt], 0, 0, 0);
            }
        }
    }
    // cross-lane lsum reduction over the 16 c-lanes
#pragma unroll
    for (int a = 0; a < 4; a++)
#pragma unroll
        for (int r = 0; r < 4; r++) {
#pragma unroll
            for (int off = 1; off < 16; off <<= 1) lsum[a][r] += __shfl_xor(lsum[a][r], off);
        }
#pragma unroll
    for (int a = 0; a < 4; a++)
#pragma unroll
        for (int nt = 0; nt < 4; nt++)
#pragma unroll
            for (int r = 0; r < 4; r++) {
                int l = q0b + a * 16 + quad * 4 + r;
                AO[((long)(b * L_ + l)) * D_ + hq * HD_ + nt * 16 + c] =
                    (bf16)(o[a][nt][r] / lsum[a][r]);
            }
}

// ---------------------------------------------------------------------------
extern "C" void kernel_launch(void* const* d_in, const int* in_sizes, int n_in,
                              void* d_out, int out_size, void* d_ws, size_t ws_size,
                              hipStream_t stream) {
    (void)in_sizes; (void)n_in; (void)out_size; (void)ws_size;
    const float* x  = (const float*)d_in[0];
    const float* wq = (const float*)d_in[1];
    const float* wk = (const float*)d_in[2];
    const float* wv = (const float*)d_in[3];
    const float* wo = (const float*)d_in[4];
    const int* pos  = (const int*)d_in[5];

    bf16* ws    = (bf16*)d_ws;
    bf16* xb    = ws;                   // [3584][2048] bf16 x  (reused as AO)
    bf16* wqkvT = ws + 7340032L;        // [3072][2048]  (wq^T | wk^T | wv^T)
    bf16* woT   = ws + 13631488L;       // [2048][2048]
    bf16* QKV   = ws + 17825792L;       // [3584][3072]
    bf16* Vt    = ws + 28835840L;       // [4][8][64][896]
    bf16* AO    = xb;
    float2* cs  = (float2*)(ws + 30670848L);  // [896][32]

    convert_to_bf16<<<dim3(7168), 256, 0, stream>>>(x, xb);
    rope_cs_kernel<<<dim3(112), dim3(256), 0, stream>>>(pos, cs);

    transpose_cvt<<<dim3(32, 32), 256, 0, stream>>>(wq, (ushort*)wqkvT, 2048, 2048);
    transpose_cvt<<<dim3(8, 32), 256, 0, stream>>>(wk, (ushort*)(wqkvT + 4194304L), 512, 2048);
    transpose_cvt<<<dim3(8, 32), 256, 0, stream>>>(wv, (ushort*)(wqkvT + 5242880L), 512, 2048);
    transpose_cvt<<<dim3(32, 32), 256, 0, stream>>>(wo, (ushort*)woT, 2048, 2048);

    // QKV projection: [3584][2048] x [3072][2048]^T -> [3584][3072] bf16
    gemm256<<<dim3(12, 14), 512, 0, stream>>>(xb, wqkvT, QKV, NQKV, D_, 0);

    rope_apply<<<dim3(4480), 256, 0, stream>>>(QKV, cs);

    // V cols of QKV -> Vt[b][h][64][896]
    transpose_u16<<<dim3(1, 14, 32), 256, 0, stream>>>(
        (const ushort*)(QKV + 2560), (ushort*)Vt, 3072, 896,
        896L * 3072, 64, 8L * 57344, 57344);

    attn_kernel<<<dim3(14, 8, 4), 256, 0, stream>>>(QKV, Vt, AO);

    // output projection: [3584][2048] x [2048][2048]^T -> [3584][2048] fp32
    gemm256x128<<<dim3(16, 14), 512, 0, stream>>>(AO, woT, (float*)d_out, D_, D_);
}

// Round 6
// 268.268 us; speedup vs baseline: 1.1440x; 1.0657x over previous
//
#include <hip/hip_runtime.h>
#include <hip/hip_bf16.h>
#include <cstdint>

typedef __bf16 bf16;
typedef __bf16 bf16x8 __attribute__((ext_vector_type(8)));
typedef float floatx4 __attribute__((ext_vector_type(4)));

#define B_   4
#define L_   896
#define D_   2048
#define HQ_  32
#define HKV_ 8
#define HD_  64
#define NQKV 3072   /* 2048 q + 512 k + 512 v */
#define M_   3584   /* B_*L_ */

// async global->LDS, 16B per lane. LDS dst must be wave-uniform base + lane*16.
__device__ inline void gl_lds16(const bf16* g, bf16* l) {
    __builtin_amdgcn_global_load_lds(
        (const __attribute__((address_space(1))) void*)g,
        (__attribute__((address_space(3))) void*)l, 16, 0, 0);
}

__device__ inline void barrier_() {
    asm volatile("" ::: "memory");
    __builtin_amdgcn_s_barrier();
    asm volatile("" ::: "memory");
}

// ---------------------------------------------------------------------------
// fp32 -> bf16 (x only). Grid: n/1024 blocks.
// ---------------------------------------------------------------------------
__global__ __launch_bounds__(256) void convert_to_bf16(const float* __restrict__ in,
                                                       bf16* __restrict__ out) {
    long q = (long)blockIdx.x * 256 + threadIdx.x;
    float4 v = ((const float4*)in)[q];
    union { bf16 b[4]; ushort4 u; } w;
    w.b[0] = (bf16)v.x; w.b[1] = (bf16)v.y; w.b[2] = (bf16)v.z; w.b[3] = (bf16)v.w;
    ((ushort4*)out)[q] = w.u;
}

// ---------------------------------------------------------------------------
// RoPE cos/sin table: [L][32] float2
// ---------------------------------------------------------------------------
__global__ __launch_bounds__(256) void rope_cs_kernel(const int* __restrict__ pos_ids,
                                                      float2* __restrict__ cs) {
    int idx = blockIdx.x * 256 + threadIdx.x;
    if (idx >= L_ * 32) return;
    int l = idx >> 5, i = idx & 31;
    float p = (float)pos_ids[l];
    float inv = exp2f(-(float)i * (13.287712379549449f / 32.0f));  // 10000^(-i/32)
    float a = p * inv;
    cs[idx] = make_float2(cosf(a), sinf(a));
}

// ---------------------------------------------------------------------------
// Standalone RoPE, vectorized: 4 pairs (16 B) per thread, in place on
// QKV cols [0,2560). Grid: 3584*320/256 = 4480 blocks.
// ---------------------------------------------------------------------------
__global__ __launch_bounds__(256) void rope_apply(bf16* __restrict__ QKV,
                                                  const float2* __restrict__ cs) {
    int idx = blockIdx.x * 256 + threadIdx.x;   // [0, 3584*320)
    int m = idx / 320, g = idx - m * 320;       // 4-pair group; cols 8g..8g+7
    int l = m % L_;
    int hp = (g * 4) & 31;                      // head-local pair idx of pair0
    const float2* ct = &cs[l * 32 + hp];
    bf16* p = QKV + (long)m * NQKV + g * 8;
    bf16x8 v = *(bf16x8*)p;
    bf16x8 w;
#pragma unroll
    for (int i = 0; i < 4; i++) {
        float2 csv = ct[i];
        float x1 = (float)v[2 * i], x2 = (float)v[2 * i + 1];
        w[2 * i]     = (bf16)(x1 * csv.x - x2 * csv.y);
        w[2 * i + 1] = (bf16)(x1 * csv.y + x2 * csv.x);
    }
    *(bf16x8*)p = w;
}

// ---------------------------------------------------------------------------
// Fused fp32->bf16 + 64x64 tiled transpose. in fp32 [R][C] -> out bf16 [C][R].
// ---------------------------------------------------------------------------
__global__ __launch_bounds__(256) void transpose_cvt(
    const float* __restrict__ in, ushort* __restrict__ out, int C, int R) {
    __shared__ ushort t[64][72];
    int tid = threadIdx.x;
    int tr = tid >> 4, tc = (tid & 15) << 2;
    long r0 = (long)blockIdx.y << 6, c0 = (long)blockIdx.x << 6;
#pragma unroll
    for (int i = 0; i < 4; ++i) {
        float4 v = *(const float4*)&in[(r0 + tr + i * 16) * C + c0 + tc];
        union { bf16 b[4]; ushort4 u; } w;
        w.b[0] = (bf16)v.x; w.b[1] = (bf16)v.y; w.b[2] = (bf16)v.z; w.b[3] = (bf16)v.w;
        *(ushort4*)&t[tr + i * 16][tc] = w.u;
    }
    __syncthreads();
#pragma unroll
    for (int i = 0; i < 4; ++i) {
        ushort4 w;
        w.x = t[tc + 0][tr + i * 16];
        w.y = t[tc + 1][tr + i * 16];
        w.z = t[tc + 2][tr + i * 16];
        w.w = t[tc + 3][tr + i * 16];
        *(ushort4*)&out[(c0 + tr + i * 16) * R + r0 + tc] = w;
    }
}

// ---------------------------------------------------------------------------
// bf16 64x64 tiled transpose (for V -> Vt). z-batch as before.
// ---------------------------------------------------------------------------
__global__ __launch_bounds__(256) void transpose_u16(
    const ushort* __restrict__ in, ushort* __restrict__ out,
    int ld_in, int ld_out, long is1, long is2, long os1, long os2) {
    __shared__ ushort t[64][72];
    int z = blockIdx.z;
    const ushort* ip = in + (long)(z >> 3) * is1 + (long)(z & 7) * is2;
    ushort* op = out + (long)(z >> 3) * os1 + (long)(z & 7) * os2;
    int tid = threadIdx.x;
    int tr = tid >> 4, tc = (tid & 15) << 2;
    long r0 = (long)blockIdx.y << 6, c0 = (long)blockIdx.x << 6;
#pragma unroll
    for (int i = 0; i < 4; ++i) {
        ushort4 v = *(const ushort4*)&ip[(r0 + tr + i * 16) * ld_in + c0 + tc];
        *(ushort4*)&t[tr + i * 16][tc] = v;
    }
    __syncthreads();
#pragma unroll
    for (int i = 0; i < 4; ++i) {
        ushort4 w;
        w.x = t[tc + 0][tr + i * 16];
        w.y = t[tc + 1][tr + i * 16];
        w.z = t[tc + 2][tr + i * 16];
        w.w = t[tc + 3][tr + i * 16];
        *(ushort4*)&op[(c0 + tr + i * 16) * ld_out + r0 + tc] = w;
    }
}

// ===========================================================================
// gemm224<JF,OUTF32>: C[M][N] = A[M][K] * Bt[N][K]^T with FULL grid fill.
// BM=224, BN=JF*64, BK=64 -> grid (N/BN) x (M/224) = exactly 256 blocks for
// both call sites (QKV: JF=3 -> 16x16; wo: JF=2 -> 16x16). 8 waves (2Mx4N),
// wave tile 112 x JF*16 = 7 x JF 16x16-frags. 2 phases per K-tile.
//
// LDS (dbuf): A 2x[224][64] (56KB) + B 2x[JF*64][64] (JF*16KB) = 104/88 KB.
// 3-bit slot swizzle as before: phys_slot = log_slot ^ (row&7); staged via
// pre-swizzled global col, read via XOR'd col (both-sides, rule #21).
//
// Staging rounds (512 thr x 16B = 64 rows/round): A = 3 full rounds + 1
// predicated round (tid<256, rows 192..223; wave-uniform). B = JF rounds.
// Per-wave issue counts differ (waves 0-3: 4 A-loads, waves 4-7: 3), but the
// counted wait vmcnt(JF) pins only the NEWEST JF loads (B(t+2)) -> uniform.
//
// Schedule per K-tile t:  [A(t) in ldsA[t&1], B(t) in ldsB[t&1]]
//   p1: ld af(i=0..3) + bq(all) | stage A(t+1)->nxt | bar,lgkm0 | MFMA i0-3
//   p2: ld af(i=4..6)           | stage B(t+2)->cur | bar,lgkm0 | MFMA i4-6
//       vmcnt(JF) (tail: vmcnt(0)) | bar
// Ledger at p2-wait: [B(t+1):JF][A(t+1):4|3][B(t+2):JF] -> vmcnt(JF) drains
// A(t+1)+B(t+1); B(t+2)-into-ldsB[cur] is safe (B[cur] reads done by p1 bar2).
// ===========================================================================
template <int JF, int OUTF32>
__global__ __launch_bounds__(512, 2) void gemm224(
    const bf16* __restrict__ A, const bf16* __restrict__ Bt, void* __restrict__ C,
    int Ntot, int Ktot) {
    __shared__ bf16 ldsA[2][224 * 64];
    __shared__ bf16 ldsB[2][JF * 64 * 64];
    const int tid = threadIdx.x;
    const int lane = tid & 63;
    const int quad = lane >> 4, l16 = lane & 15;
    const int w = tid >> 6;
    const int wr = w >> 2, wc = w & 3;

    // XCD-aware swizzle; nwg == 256 here (multiple of 8)
    const int gx = gridDim.x;
    const int nwg = gx * gridDim.y;
    int orig = blockIdx.y * gx + blockIdx.x;
    int q8 = nwg >> 3, r8 = nwg & 7;
    int xcd = orig & 7, lid = orig >> 3;
    int wg = (xcd < r8 ? xcd * (q8 + 1) : r8 * (q8 + 1) + (xcd - r8) * q8) + lid;
    const long m0 = (long)(wg / gx) * 224;
    const long n0 = (long)(wg % gx) * (JF * 64);

    const long rowK = Ktot;
    // staging: round r covers rows 64r + (tid>>3); slot tid&7, pre-swizzled col
    const int srow = tid >> 3;
    const int scol = ((tid & 7) ^ (srow & 7)) << 3;
    const bf16* baseA = A  + (m0 + srow) * rowK + scol;
    const bf16* baseB = Bt + (n0 + srow) * rowK + scol;
    bf16* const dA = (bf16*)ldsA + tid * 8;     // + buf*224*64 + round*4096
    bf16* const dB = (bf16*)ldsB + tid * 8;

    // ds_read swizzle: col = ((ks*4+quad) ^ (row&7))<<3; row&7 == l16&7
    const int m7 = l16 & 7;
    const int col0 = ((0 + quad) ^ m7) << 3;
    const int col1 = ((4 + quad) ^ m7) << 3;
    const int abase = wr * 112 + l16;           // 112 = 7*16, &7 == l16&7
    const int bbase = wc * (JF * 16) + l16;     // JF*16 mult of 16

    floatx4 acc[7][JF];
#pragma unroll
    for (int i = 0; i < 7; ++i)
#pragma unroll
        for (int j = 0; j < JF; ++j)
#pragma unroll
            for (int r = 0; r < 4; ++r) acc[i][j][r] = 0.f;

    bf16x8 af0[4][2], af1[3][2], bq[JF][2];

    const int T = Ktot >> 6;

    // prologue: A(0)->bufA0, B(0)->bufB0, B(1)->bufB1
    {
        gl_lds16(baseA,              dA);
        gl_lds16(baseA + 64 * rowK,  dA + 4096);
        gl_lds16(baseA + 128 * rowK, dA + 8192);
        if (tid < 256) gl_lds16(baseA + 192 * rowK, dA + 12288);
#pragma unroll
        for (int r = 0; r < JF; ++r) gl_lds16(baseB + r * 64 * rowK, dB + r * 4096);
#pragma unroll
        for (int r = 0; r < JF; ++r) gl_lds16(baseB + 64 + r * 64 * rowK,
                                              dB + JF * 4096 + r * 4096);
    }
    if (JF == 3) asm volatile("s_waitcnt vmcnt(3)" ::: "memory");
    else         asm volatile("s_waitcnt vmcnt(2)" ::: "memory");
    barrier_();

    for (int t = 0; t < T; ++t) {
        const int cur = t & 1, nxt = cur ^ 1;
        const bf16* pa = &ldsA[cur][0];
        const bf16* pb = &ldsB[cur][0];
        const long koff  = (long)(t + 1) * 64;
        const long koff2 = (long)(t + 2) * 64;

        // ---- p1: af i=0..3 + bq all | stage A(t+1) -> nxt ----
#pragma unroll
        for (int i = 0; i < 4; ++i) {
            const bf16* rp = &pa[(abase + i * 16) * 64];
            af0[i][0] = *(const bf16x8*)&rp[col0];
            af0[i][1] = *(const bf16x8*)&rp[col1];
        }
#pragma unroll
        for (int j = 0; j < JF; ++j) {
            const bf16* rp = &pb[(bbase + j * 16) * 64];
            bq[j][0] = *(const bf16x8*)&rp[col0];
            bq[j][1] = *(const bf16x8*)&rp[col1];
        }
        if (t + 1 < T) {
            const bf16* g = baseA + koff;
            bf16* l = dA + nxt * (224 * 64);
            gl_lds16(g,              l);
            gl_lds16(g + 64 * rowK,  l + 4096);
            gl_lds16(g + 128 * rowK, l + 8192);
            if (tid < 256) gl_lds16(g + 192 * rowK, l + 12288);
        }
        barrier_();
        asm volatile("s_waitcnt lgkmcnt(0)" ::: "memory");
        __builtin_amdgcn_sched_barrier(0);
        __builtin_amdgcn_s_setprio(1);
#pragma unroll
        for (int i = 0; i < 4; ++i)
#pragma unroll
            for (int j = 0; j < JF; ++j) {
                floatx4 c = acc[i][j];
                c = __builtin_amdgcn_mfma_f32_16x16x32_bf16(af0[i][0], bq[j][0], c, 0, 0, 0);
                c = __builtin_amdgcn_mfma_f32_16x16x32_bf16(af0[i][1], bq[j][1], c, 0, 0, 0);
                acc[i][j] = c;
            }
        __builtin_amdgcn_s_setprio(0);
        barrier_();

        // ---- p2: af i=4..6 | stage B(t+2) -> cur ----
#pragma unroll
        for (int i = 0; i < 3; ++i) {
            const bf16* rp = &pa[(abase + (4 + i) * 16) * 64];
            af1[i][0] = *(const bf16x8*)&rp[col0];
            af1[i][1] = *(const bf16x8*)&rp[col1];
        }
        if (t + 2 < T) {
            const bf16* g = baseB + koff2;
            bf16* l = dB + cur * (JF * 64 * 64);
#pragma unroll
            for (int r = 0; r < JF; ++r) gl_lds16(g + r * 64 * rowK, l + r * 4096);
        }
        barrier_();
        asm volatile("s_waitcnt lgkmcnt(0)" ::: "memory");
        __builtin_amdgcn_sched_barrier(0);
        __builtin_amdgcn_s_setprio(1);
#pragma unroll
        for (int i = 0; i < 3; ++i)
#pragma unroll
            for (int j = 0; j < JF; ++j) {
                floatx4 c = acc[4 + i][j];
                c = __builtin_amdgcn_mfma_f32_16x16x32_bf16(af1[i][0], bq[j][0], c, 0, 0, 0);
                c = __builtin_amdgcn_mfma_f32_16x16x32_bf16(af1[i][1], bq[j][1], c, 0, 0, 0);
                acc[4 + i][j] = c;
            }
        __builtin_amdgcn_s_setprio(0);
        if (t + 2 < T) {
            if (JF == 3) asm volatile("s_waitcnt vmcnt(3)" ::: "memory");
            else         asm volatile("s_waitcnt vmcnt(2)" ::: "memory");
        } else {
            asm volatile("s_waitcnt vmcnt(0)" ::: "memory");
        }
        barrier_();
    }

    // epilogue: C/D layout row = quad*4 + r, col = l16
#pragma unroll
    for (int i = 0; i < 7; ++i)
#pragma unroll
        for (int j = 0; j < JF; ++j)
#pragma unroll
            for (int r = 0; r < 4; ++r) {
                long m = m0 + wr * 112 + i * 16 + quad * 4 + r;
                long n = n0 + wc * (JF * 16) + j * 16 + l16;
                if (OUTF32) ((float*)C)[m * Ntot + n] = acc[i][j][r];
                else        ((bf16*)C)[m * Ntot + n] = (bf16)acc[i][j][r];
            }
}

// ---------------------------------------------------------------------------
// Flash attention, GQA-group blocking (verified round 5): one block = 4 waves
// = the 4 q-heads sharing a kv-head; shared K/V staging; K/V frags hoisted.
// Grid: (14, 8, 4). LDS = 55.3 KB. Fixed-max softmax p = exp(s/8 - 12).
// ---------------------------------------------------------------------------
__global__ __launch_bounds__(256) void attn_kernel(
    const bf16* __restrict__ QKV,  // [M][3072]: q(rope'd) | k(rope'd) | v
    const bf16* __restrict__ Vt,   // [B][HKV][64][896]
    bf16* __restrict__ AO) {       // [M][2048]
    __shared__ bf16 Ks[64 * 72];
    __shared__ bf16 Vs[64 * 72];
    __shared__ bf16 Ps[4][64 * 72];
    const int tid  = threadIdx.x;
    const int wid  = tid >> 6, lane = tid & 63;
    const int quad = lane >> 4, c = lane & 15;
    const int b = blockIdx.z, kvh = blockIdx.y;
    const int hq = kvh * 4 + wid;
    const int q0b = blockIdx.x * 64;
    bf16* ps = &Ps[wid][0];

    const bf16* Qb = QKV + ((long)(b * L_ + q0b)) * NQKV + hq * HD_;
    const bf16* Kb = QKV + ((long)(b * L_)) * NQKV + D_ + kvh * HD_;
    const bf16* Vb = Vt + ((long)(b * HKV_ + kvh)) * (HD_ * L_);

    bf16x8 qf[4][2];
#pragma unroll
    for (int a = 0; a < 4; a++) {
        qf[a][0] = *(const bf16x8*)&Qb[(long)(a * 16 + c) * NQKV + quad * 8];
        qf[a][1] = *(const bf16x8*)&Qb[(long)(a * 16 + c) * NQKV + 32 + quad * 8];
    }

    float lsum[4][4];
    floatx4 o[4][4];
#pragma unroll
    for (int a = 0; a < 4; a++)
#pragma unroll
        for (int r = 0; r < 4; r++) lsum[a][r] = 0.f;
#pragma unroll
    for (int a = 0; a < 4; a++)
#pragma unroll
        for (int nt = 0; nt < 4; nt++)
#pragma unroll
            for (int r = 0; r < 4; r++) o[a][nt][r] = 0.f;

    int fe[4][4];
#pragma unroll
    for (int a = 0; a < 4; a++)
#pragma unroll
        for (int r = 0; r < 4; r++) {
            int l = q0b + a * 16 + quad * 4 + r;
            fe[a][r] = (l / 7 + 1) * 7;
        }
    const int kend = ((q0b + 63) / 7 + 1) * 7;

    const int srow = tid >> 3, schunk = (tid & 7) << 3;

    for (int k0 = 0; k0 < kend; k0 += 64) {
        bf16x8 kg0 = *(const bf16x8*)&Kb[(long)(k0 + srow) * NQKV + schunk];
        bf16x8 kg1 = *(const bf16x8*)&Kb[(long)(k0 + 32 + srow) * NQKV + schunk];
        bf16x8 vg0 = *(const bf16x8*)&Vb[(long)srow * L_ + k0 + schunk];
        bf16x8 vg1 = *(const bf16x8*)&Vb[(long)(srow + 32) * L_ + k0 + schunk];
        __syncthreads();
        *(bf16x8*)&Ks[srow * 72 + schunk]        = kg0;
        *(bf16x8*)&Ks[(srow + 32) * 72 + schunk] = kg1;
        *(bf16x8*)&Vs[srow * 72 + schunk]        = vg0;
        *(bf16x8*)&Vs[(srow + 32) * 72 + schunk] = vg1;
        __syncthreads();

        bf16x8 kf[4][2];
#pragma unroll
        for (int n = 0; n < 4; n++) {
            kf[n][0] = *(bf16x8*)&Ks[(n * 16 + c) * 72 + quad * 8];
            kf[n][1] = *(bf16x8*)&Ks[(n * 16 + c) * 72 + 32 + quad * 8];
        }
#pragma unroll
        for (int a = 0; a < 4; a++) {
            floatx4 s[4];
#pragma unroll
            for (int n = 0; n < 4; n++) {
#pragma unroll
                for (int r = 0; r < 4; r++) s[n][r] = 0.f;
                s[n] = __builtin_amdgcn_mfma_f32_16x16x32_bf16(qf[a][0], kf[n][0], s[n], 0, 0, 0);
                s[n] = __builtin_amdgcn_mfma_f32_16x16x32_bf16(qf[a][1], kf[n][1], s[n], 0, 0, 0);
            }
#pragma unroll
            for (int n = 0; n < 4; n++) {
                const int key = k0 + n * 16 + c;
#pragma unroll
                for (int r = 0; r < 4; r++) {
                    float e = __expf(fmaf(s[n][r], 0.125f, -12.0f));
                    e = (key < fe[a][r]) ? e : 0.f;
                    lsum[a][r] += e;
                    ps[(a * 16 + quad * 4 + r) * 72 + n * 16 + c] = (bf16)e;
                }
            }
        }
        bf16x8 vf[4][2];
#pragma unroll
        for (int nt = 0; nt < 4; nt++) {
            vf[nt][0] = *(bf16x8*)&Vs[(nt * 16 + c) * 72 + quad * 8];
            vf[nt][1] = *(bf16x8*)&Vs[(nt * 16 + c) * 72 + 32 + quad * 8];
        }
#pragma unroll
        for (int a = 0; a < 4; a++) {
            bf16x8 pf0 = *(bf16x8*)&ps[(a * 16 + c) * 72 + quad * 8];
            bf16x8 pf1 = *(bf16x8*)&ps[(a * 16 + c) * 72 + 32 + quad * 8];
#pragma unroll
            for (int nt = 0; nt < 4; nt++) {
                o[a][nt] = __builtin_amdgcn_mfma_f32_16x16x32_bf16(pf0, vf[nt][0], o[a][nt], 0, 0, 0);
                o[a][nt] = __builtin_amdgcn_mfma_f32_16x16x32_bf16(pf1, vf[nt][1], o[a][nt], 0, 0, 0);
            }
        }
    }
#pragma unroll
    for (int a = 0; a < 4; a++)
#pragma unroll
        for (int r = 0; r < 4; r++) {
#pragma unroll
            for (int off = 1; off < 16; off <<= 1) lsum[a][r] += __shfl_xor(lsum[a][r], off);
        }
#pragma unroll
    for (int a = 0; a < 4; a++)
#pragma unroll
        for (int nt = 0; nt < 4; nt++)
#pragma unroll
            for (int r = 0; r < 4; r++) {
                int l = q0b + a * 16 + quad * 4 + r;
                AO[((long)(b * L_ + l)) * D_ + hq * HD_ + nt * 16 + c] =
                    (bf16)(o[a][nt][r] / lsum[a][r]);
            }
}

// ---------------------------------------------------------------------------
extern "C" void kernel_launch(void* const* d_in, const int* in_sizes, int n_in,
                              void* d_out, int out_size, void* d_ws, size_t ws_size,
                              hipStream_t stream) {
    (void)in_sizes; (void)n_in; (void)out_size; (void)ws_size;
    const float* x  = (const float*)d_in[0];
    const float* wq = (const float*)d_in[1];
    const float* wk = (const float*)d_in[2];
    const float* wv = (const float*)d_in[3];
    const float* wo = (const float*)d_in[4];
    const int* pos  = (const int*)d_in[5];

    bf16* ws    = (bf16*)d_ws;
    bf16* xb    = ws;                   // [3584][2048] bf16 x  (reused as AO)
    bf16* wqkvT = ws + 7340032L;        // [3072][2048]  (wq^T | wk^T | wv^T)
    bf16* woT   = ws + 13631488L;       // [2048][2048]
    bf16* QKV   = ws + 17825792L;       // [3584][3072]
    bf16* Vt    = ws + 28835840L;       // [4][8][64][896]
    bf16* AO    = xb;
    float2* cs  = (float2*)(ws + 30670848L);  // [896][32]

    convert_to_bf16<<<dim3(7168), 256, 0, stream>>>(x, xb);
    rope_cs_kernel<<<dim3(112), dim3(256), 0, stream>>>(pos, cs);

    transpose_cvt<<<dim3(32, 32), 256, 0, stream>>>(wq, (ushort*)wqkvT, 2048, 2048);
    transpose_cvt<<<dim3(8, 32), 256, 0, stream>>>(wk, (ushort*)(wqkvT + 4194304L), 512, 2048);
    transpose_cvt<<<dim3(8, 32), 256, 0, stream>>>(wv, (ushort*)(wqkvT + 5242880L), 512, 2048);
    transpose_cvt<<<dim3(32, 32), 256, 0, stream>>>(wo, (ushort*)woT, 2048, 2048);

    // QKV projection: [3584][2048] x [3072][2048]^T -> [3584][3072] bf16
    // grid 16x16 = 256 blocks (full fill), tile 224x192
    gemm224<3, 0><<<dim3(16, 16), 512, 0, stream>>>(xb, wqkvT, QKV, NQKV, D_);

    rope_apply<<<dim3(4480), 256, 0, stream>>>(QKV, cs);

    // V cols of QKV -> Vt[b][h][64][896]
    transpose_u16<<<dim3(1, 14, 32), 256, 0, stream>>>(
        (const ushort*)(QKV + 2560), (ushort*)Vt, 3072, 896,
        896L * 3072, 64, 8L * 57344, 57344);

    attn_kernel<<<dim3(14, 8, 4), 256, 0, stream>>>(QKV, Vt, AO);

    // output projection: [3584][2048] x [2048][2048]^T -> [3584][2048] fp32
    // grid 16x16 = 256 blocks (full fill), tile 224x128
    gemm224<2, 1><<<dim3(16, 16), 512, 0, stream>>>(AO, woT, d_out, D_, D_);
}

// Round 7
// 266.663 us; speedup vs baseline: 1.1509x; 1.0060x over previous
//
#include <hip/hip_runtime.h>
#include <hip/hip_bf16.h>
#include <cstdint>

typedef __bf16 bf16;
typedef __bf16 bf16x8 __attribute__((ext_vector_type(8)));
typedef float floatx4 __attribute__((ext_vector_type(4)));

#define B_   4
#define L_   896
#define D_   2048
#define HQ_  32
#define HKV_ 8
#define HD_  64
#define NQKV 3072   /* 2048 q + 512 k + 512 v */
#define M_   3584   /* B_*L_ */

// async global->LDS, 16B per lane. LDS dst must be wave-uniform base + lane*16.
__device__ inline void gl_lds16(const bf16* g, bf16* l) {
    __builtin_amdgcn_global_load_lds(
        (const __attribute__((address_space(1))) void*)g,
        (__attribute__((address_space(3))) void*)l, 16, 0, 0);
}

__device__ inline void barrier_() {
    asm volatile("" ::: "memory");
    __builtin_amdgcn_s_barrier();
    asm volatile("" ::: "memory");
}

// ---------------------------------------------------------------------------
// fp32 -> bf16 (x only). Grid: n/1024 blocks.
// ---------------------------------------------------------------------------
__global__ __launch_bounds__(256) void convert_to_bf16(const float* __restrict__ in,
                                                       bf16* __restrict__ out) {
    long q = (long)blockIdx.x * 256 + threadIdx.x;
    float4 v = ((const float4*)in)[q];
    union { bf16 b[4]; ushort4 u; } w;
    w.b[0] = (bf16)v.x; w.b[1] = (bf16)v.y; w.b[2] = (bf16)v.z; w.b[3] = (bf16)v.w;
    ((ushort4*)out)[q] = w.u;
}

// ---------------------------------------------------------------------------
// RoPE cos/sin table: [L][32] float2
// ---------------------------------------------------------------------------
__global__ __launch_bounds__(256) void rope_cs_kernel(const int* __restrict__ pos_ids,
                                                      float2* __restrict__ cs) {
    int idx = blockIdx.x * 256 + threadIdx.x;
    if (idx >= L_ * 32) return;
    int l = idx >> 5, i = idx & 31;
    float p = (float)pos_ids[l];
    float inv = exp2f(-(float)i * (13.287712379549449f / 32.0f));  // 10000^(-i/32)
    float a = p * inv;
    cs[idx] = make_float2(cosf(a), sinf(a));
}

// ---------------------------------------------------------------------------
// Standalone RoPE, vectorized: 4 pairs (16 B) per thread, in place on
// QKV cols [0,2560). Grid: 3584*320/256 = 4480 blocks.
// ---------------------------------------------------------------------------
__global__ __launch_bounds__(256) void rope_apply(bf16* __restrict__ QKV,
                                                  const float2* __restrict__ cs) {
    int idx = blockIdx.x * 256 + threadIdx.x;   // [0, 3584*320)
    int m = idx / 320, g = idx - m * 320;       // 4-pair group; cols 8g..8g+7
    int l = m % L_;
    int hp = (g * 4) & 31;                      // head-local pair idx of pair0
    const float2* ct = &cs[l * 32 + hp];
    bf16* p = QKV + (long)m * NQKV + g * 8;
    bf16x8 v = *(bf16x8*)p;
    bf16x8 w;
#pragma unroll
    for (int i = 0; i < 4; i++) {
        float2 csv = ct[i];
        float x1 = (float)v[2 * i], x2 = (float)v[2 * i + 1];
        w[2 * i]     = (bf16)(x1 * csv.x - x2 * csv.y);
        w[2 * i + 1] = (bf16)(x1 * csv.y + x2 * csv.x);
    }
    *(bf16x8*)p = w;
}

// ---------------------------------------------------------------------------
// Fused fp32->bf16 + 64x64 tiled transpose. in fp32 [R][C] -> out bf16 [C][R].
// ---------------------------------------------------------------------------
__global__ __launch_bounds__(256) void transpose_cvt(
    const float* __restrict__ in, ushort* __restrict__ out, int C, int R) {
    __shared__ ushort t[64][72];
    int tid = threadIdx.x;
    int tr = tid >> 4, tc = (tid & 15) << 2;
    long r0 = (long)blockIdx.y << 6, c0 = (long)blockIdx.x << 6;
#pragma unroll
    for (int i = 0; i < 4; ++i) {
        float4 v = *(const float4*)&in[(r0 + tr + i * 16) * C + c0 + tc];
        union { bf16 b[4]; ushort4 u; } w;
        w.b[0] = (bf16)v.x; w.b[1] = (bf16)v.y; w.b[2] = (bf16)v.z; w.b[3] = (bf16)v.w;
        *(ushort4*)&t[tr + i * 16][tc] = w.u;
    }
    __syncthreads();
#pragma unroll
    for (int i = 0; i < 4; ++i) {
        ushort4 w;
        w.x = t[tc + 0][tr + i * 16];
        w.y = t[tc + 1][tr + i * 16];
        w.z = t[tc + 2][tr + i * 16];
        w.w = t[tc + 3][tr + i * 16];
        *(ushort4*)&out[(c0 + tr + i * 16) * R + r0 + tc] = w;
    }
}

// ---------------------------------------------------------------------------
// bf16 64x64 tiled transpose (for V -> Vt). z-batch as before.
// ---------------------------------------------------------------------------
__global__ __launch_bounds__(256) void transpose_u16(
    const ushort* __restrict__ in, ushort* __restrict__ out,
    int ld_in, int ld_out, long is1, long is2, long os1, long os2) {
    __shared__ ushort t[64][72];
    int z = blockIdx.z;
    const ushort* ip = in + (long)(z >> 3) * is1 + (long)(z & 7) * is2;
    ushort* op = out + (long)(z >> 3) * os1 + (long)(z & 7) * os2;
    int tid = threadIdx.x;
    int tr = tid >> 4, tc = (tid & 15) << 2;
    long r0 = (long)blockIdx.y << 6, c0 = (long)blockIdx.x << 6;
#pragma unroll
    for (int i = 0; i < 4; ++i) {
        ushort4 v = *(const ushort4*)&ip[(r0 + tr + i * 16) * ld_in + c0 + tc];
        *(ushort4*)&t[tr + i * 16][tc] = v;
    }
    __syncthreads();
#pragma unroll
    for (int i = 0; i < 4; ++i) {
        ushort4 w;
        w.x = t[tc + 0][tr + i * 16];
        w.y = t[tc + 1][tr + i * 16];
        w.z = t[tc + 2][tr + i * 16];
        w.w = t[tc + 3][tr + i * 16];
        *(ushort4*)&op[(c0 + tr + i * 16) * ld_out + r0 + tc] = w;
    }
}

// ===========================================================================
// gemm224<JF,OUTF32>: unchanged (verified round 6). Full 256-block fill.
// ===========================================================================
template <int JF, int OUTF32>
__global__ __launch_bounds__(512, 2) void gemm224(
    const bf16* __restrict__ A, const bf16* __restrict__ Bt, void* __restrict__ C,
    int Ntot, int Ktot) {
    __shared__ bf16 ldsA[2][224 * 64];
    __shared__ bf16 ldsB[2][JF * 64 * 64];
    const int tid = threadIdx.x;
    const int lane = tid & 63;
    const int quad = lane >> 4, l16 = lane & 15;
    const int w = tid >> 6;
    const int wr = w >> 2, wc = w & 3;

    const int gx = gridDim.x;
    const int nwg = gx * gridDim.y;
    int orig = blockIdx.y * gx + blockIdx.x;
    int q8 = nwg >> 3, r8 = nwg & 7;
    int xcd = orig & 7, lid = orig >> 3;
    int wg = (xcd < r8 ? xcd * (q8 + 1) : r8 * (q8 + 1) + (xcd - r8) * q8) + lid;
    const long m0 = (long)(wg / gx) * 224;
    const long n0 = (long)(wg % gx) * (JF * 64);

    const long rowK = Ktot;
    const int srow = tid >> 3;
    const int scol = ((tid & 7) ^ (srow & 7)) << 3;
    const bf16* baseA = A  + (m0 + srow) * rowK + scol;
    const bf16* baseB = Bt + (n0 + srow) * rowK + scol;
    bf16* const dA = (bf16*)ldsA + tid * 8;
    bf16* const dB = (bf16*)ldsB + tid * 8;

    const int m7 = l16 & 7;
    const int col0 = ((0 + quad) ^ m7) << 3;
    const int col1 = ((4 + quad) ^ m7) << 3;
    const int abase = wr * 112 + l16;
    const int bbase = wc * (JF * 16) + l16;

    floatx4 acc[7][JF];
#pragma unroll
    for (int i = 0; i < 7; ++i)
#pragma unroll
        for (int j = 0; j < JF; ++j)
#pragma unroll
            for (int r = 0; r < 4; ++r) acc[i][j][r] = 0.f;

    bf16x8 af0[4][2], af1[3][2], bq[JF][2];

    const int T = Ktot >> 6;

    {
        gl_lds16(baseA,              dA);
        gl_lds16(baseA + 64 * rowK,  dA + 4096);
        gl_lds16(baseA + 128 * rowK, dA + 8192);
        if (tid < 256) gl_lds16(baseA + 192 * rowK, dA + 12288);
#pragma unroll
        for (int r = 0; r < JF; ++r) gl_lds16(baseB + r * 64 * rowK, dB + r * 4096);
#pragma unroll
        for (int r = 0; r < JF; ++r) gl_lds16(baseB + 64 + r * 64 * rowK,
                                              dB + JF * 4096 + r * 4096);
    }
    if (JF == 3) asm volatile("s_waitcnt vmcnt(3)" ::: "memory");
    else         asm volatile("s_waitcnt vmcnt(2)" ::: "memory");
    barrier_();

    for (int t = 0; t < T; ++t) {
        const int cur = t & 1, nxt = cur ^ 1;
        const bf16* pa = &ldsA[cur][0];
        const bf16* pb = &ldsB[cur][0];
        const long koff  = (long)(t + 1) * 64;
        const long koff2 = (long)(t + 2) * 64;

#pragma unroll
        for (int i = 0; i < 4; ++i) {
            const bf16* rp = &pa[(abase + i * 16) * 64];
            af0[i][0] = *(const bf16x8*)&rp[col0];
            af0[i][1] = *(const bf16x8*)&rp[col1];
        }
#pragma unroll
        for (int j = 0; j < JF; ++j) {
            const bf16* rp = &pb[(bbase + j * 16) * 64];
            bq[j][0] = *(const bf16x8*)&rp[col0];
            bq[j][1] = *(const bf16x8*)&rp[col1];
        }
        if (t + 1 < T) {
            const bf16* g = baseA + koff;
            bf16* l = dA + nxt * (224 * 64);
            gl_lds16(g,              l);
            gl_lds16(g + 64 * rowK,  l + 4096);
            gl_lds16(g + 128 * rowK, l + 8192);
            if (tid < 256) gl_lds16(g + 192 * rowK, l + 12288);
        }
        barrier_();
        asm volatile("s_waitcnt lgkmcnt(0)" ::: "memory");
        __builtin_amdgcn_sched_barrier(0);
        __builtin_amdgcn_s_setprio(1);
#pragma unroll
        for (int i = 0; i < 4; ++i)
#pragma unroll
            for (int j = 0; j < JF; ++j) {
                floatx4 c = acc[i][j];
                c = __builtin_amdgcn_mfma_f32_16x16x32_bf16(af0[i][0], bq[j][0], c, 0, 0, 0);
                c = __builtin_amdgcn_mfma_f32_16x16x32_bf16(af0[i][1], bq[j][1], c, 0, 0, 0);
                acc[i][j] = c;
            }
        __builtin_amdgcn_s_setprio(0);
        barrier_();

#pragma unroll
        for (int i = 0; i < 3; ++i) {
            const bf16* rp = &pa[(abase + (4 + i) * 16) * 64];
            af1[i][0] = *(const bf16x8*)&rp[col0];
            af1[i][1] = *(const bf16x8*)&rp[col1];
        }
        if (t + 2 < T) {
            const bf16* g = baseB + koff2;
            bf16* l = dB + cur * (JF * 64 * 64);
#pragma unroll
            for (int r = 0; r < JF; ++r) gl_lds16(g + r * 64 * rowK, l + r * 4096);
        }
        barrier_();
        asm volatile("s_waitcnt lgkmcnt(0)" ::: "memory");
        __builtin_amdgcn_sched_barrier(0);
        __builtin_amdgcn_s_setprio(1);
#pragma unroll
        for (int i = 0; i < 3; ++i)
#pragma unroll
            for (int j = 0; j < JF; ++j) {
                floatx4 c = acc[4 + i][j];
                c = __builtin_amdgcn_mfma_f32_16x16x32_bf16(af1[i][0], bq[j][0], c, 0, 0, 0);
                c = __builtin_amdgcn_mfma_f32_16x16x32_bf16(af1[i][1], bq[j][1], c, 0, 0, 0);
                acc[4 + i][j] = c;
            }
        __builtin_amdgcn_s_setprio(0);
        if (t + 2 < T) {
            if (JF == 3) asm volatile("s_waitcnt vmcnt(3)" ::: "memory");
            else         asm volatile("s_waitcnt vmcnt(2)" ::: "memory");
        } else {
            asm volatile("s_waitcnt vmcnt(0)" ::: "memory");
        }
        barrier_();
    }

#pragma unroll
    for (int i = 0; i < 7; ++i)
#pragma unroll
        for (int j = 0; j < JF; ++j)
#pragma unroll
            for (int r = 0; r < 4; ++r) {
                long m = m0 + wr * 112 + i * 16 + quad * 4 + r;
                long n = n0 + wc * (JF * 16) + j * 16 + l16;
                if (OUTF32) ((float*)C)[m * Ntot + n] = acc[i][j][r];
                else        ((bf16*)C)[m * Ntot + n] = (bf16)acc[i][j][r];
            }
}

// ---------------------------------------------------------------------------
// Flash attention, GQA-group blocking + causal LOAD BALANCE + K/V prefetch.
//
// Balance: block work = #k-tiles ~ x+1 (x = q-tile index, 0..13). Blocks d and
// d+256 land on the same CU (XCD = d%8, CU = (d/8)%32, both invariant under
// +256), and all 448 blocks are co-resident (2/CU). Remap flat id so each
// CU's pair sums to 15 tile-units:
//   d <  192: x = d%6        (work 1..6), col = d/6
//   d <  256: x = 6 + (d&1)  (lone CUs, work 7/8 ~ mean), col = (d-192)/2
//   d >= 256: x = 13 - (d-256)%6 (work 14..9), col = (d-256)/6
// Bijective over x in [0,14) x 32 (kvh,b) columns. Heuristic only.
//
// Prefetch (T14): tile t+1's K/V global loads issue before tile t's compute;
// ~300 cyc HBM/L2 latency hides under ~1300 cyc compute. +16 VGPR.
// ---------------------------------------------------------------------------
__global__ __launch_bounds__(256) void attn_kernel(
    const bf16* __restrict__ QKV,  // [M][3072]: q(rope'd) | k(rope'd) | v
    const bf16* __restrict__ Vt,   // [B][HKV][64][896]
    bf16* __restrict__ AO) {       // [M][2048]
    __shared__ bf16 Ks[64 * 72];
    __shared__ bf16 Vs[64 * 72];
    __shared__ bf16 Ps[4][64 * 72];
    const int tid  = threadIdx.x;
    const int wid  = tid >> 6, lane = tid & 63;
    const int quad = lane >> 4, c = lane & 15;

    // ---- balanced id remap ----
    const int d = blockIdx.x + 14 * blockIdx.y + 112 * blockIdx.z;
    int x, col;
    if (d < 192)      { x = d % 6;                 col = d / 6; }
    else if (d < 256) { int j = d - 192; x = 6 + (j & 1); col = j >> 1; }
    else              { int j = d - 256; x = 13 - (j % 6); col = j / 6; }
    const int kvh = col & 7, b = col >> 3;
    const int hq = kvh * 4 + wid;
    const int q0b = x * 64;
    bf16* ps = &Ps[wid][0];

    const bf16* Qb = QKV + ((long)(b * L_ + q0b)) * NQKV + hq * HD_;
    const bf16* Kb = QKV + ((long)(b * L_)) * NQKV + D_ + kvh * HD_;
    const bf16* Vb = Vt + ((long)(b * HKV_ + kvh)) * (HD_ * L_);

    bf16x8 qf[4][2];
#pragma unroll
    for (int a = 0; a < 4; a++) {
        qf[a][0] = *(const bf16x8*)&Qb[(long)(a * 16 + c) * NQKV + quad * 8];
        qf[a][1] = *(const bf16x8*)&Qb[(long)(a * 16 + c) * NQKV + 32 + quad * 8];
    }

    float lsum[4][4];
    floatx4 o[4][4];
#pragma unroll
    for (int a = 0; a < 4; a++)
#pragma unroll
        for (int r = 0; r < 4; r++) lsum[a][r] = 0.f;
#pragma unroll
    for (int a = 0; a < 4; a++)
#pragma unroll
        for (int nt = 0; nt < 4; nt++)
#pragma unroll
            for (int r = 0; r < 4; r++) o[a][nt][r] = 0.f;

    int fe[4][4];
#pragma unroll
    for (int a = 0; a < 4; a++)
#pragma unroll
        for (int r = 0; r < 4; r++) {
            int l = q0b + a * 16 + quad * 4 + r;
            fe[a][r] = (l / 7 + 1) * 7;
        }
    const int kend = ((q0b + 63) / 7 + 1) * 7;

    const int srow = tid >> 3, schunk = (tid & 7) << 3;
    const bf16* kp0 = &Kb[(long)srow * NQKV + schunk];
    const bf16* kp1 = &Kb[(long)(32 + srow) * NQKV + schunk];
    const bf16* vp0 = &Vb[(long)srow * L_ + schunk];
    const bf16* vp1 = &Vb[(long)(srow + 32) * L_ + schunk];

    // prefetch tile 0
    bf16x8 kg0 = *(const bf16x8*)&kp0[0];
    bf16x8 kg1 = *(const bf16x8*)&kp1[0];
    bf16x8 vg0 = *(const bf16x8*)&vp0[0];
    bf16x8 vg1 = *(const bf16x8*)&vp1[0];

    for (int k0 = 0; k0 < kend; k0 += 64) {
        __syncthreads();   // previous tile's reads done before overwrite
        *(bf16x8*)&Ks[srow * 72 + schunk]        = kg0;
        *(bf16x8*)&Ks[(srow + 32) * 72 + schunk] = kg1;
        *(bf16x8*)&Vs[srow * 72 + schunk]        = vg0;
        *(bf16x8*)&Vs[(srow + 32) * 72 + schunk] = vg1;
        __syncthreads();

        // issue next tile's loads (hide latency under this tile's compute)
        const int kn = k0 + 64;
        if (kn < kend) {
            kg0 = *(const bf16x8*)&kp0[(long)kn * NQKV];
            kg1 = *(const bf16x8*)&kp1[(long)kn * NQKV];
            vg0 = *(const bf16x8*)&vp0[kn];
            vg1 = *(const bf16x8*)&vp1[kn];
        }

        bf16x8 kf[4][2];
#pragma unroll
        for (int n = 0; n < 4; n++) {
            kf[n][0] = *(bf16x8*)&Ks[(n * 16 + c) * 72 + quad * 8];
            kf[n][1] = *(bf16x8*)&Ks[(n * 16 + c) * 72 + 32 + quad * 8];
        }
#pragma unroll
        for (int a = 0; a < 4; a++) {
            floatx4 s[4];
#pragma unroll
            for (int n = 0; n < 4; n++) {
#pragma unroll
                for (int r = 0; r < 4; r++) s[n][r] = 0.f;
                s[n] = __builtin_amdgcn_mfma_f32_16x16x32_bf16(qf[a][0], kf[n][0], s[n], 0, 0, 0);
                s[n] = __builtin_amdgcn_mfma_f32_16x16x32_bf16(qf[a][1], kf[n][1], s[n], 0, 0, 0);
            }
#pragma unroll
            for (int n = 0; n < 4; n++) {
                const int key = k0 + n * 16 + c;
#pragma unroll
                for (int r = 0; r < 4; r++) {
                    // exp(s/8 - 12) = exp2(s * 0.125*log2e - 12*log2e)
                    float e = exp2f(fmaf(s[n][r], 0.18033688011112042f, -17.312340490667562f));
                    e = (key < fe[a][r]) ? e : 0.f;
                    lsum[a][r] += e;
                    ps[(a * 16 + quad * 4 + r) * 72 + n * 16 + c] = (bf16)e;
                }
            }
        }
        bf16x8 vf[4][2];
#pragma unroll
        for (int nt = 0; nt < 4; nt++) {
            vf[nt][0] = *(bf16x8*)&Vs[(nt * 16 + c) * 72 + quad * 8];
            vf[nt][1] = *(bf16x8*)&Vs[(nt * 16 + c) * 72 + 32 + quad * 8];
        }
#pragma unroll
        for (int a = 0; a < 4; a++) {
            bf16x8 pf0 = *(bf16x8*)&ps[(a * 16 + c) * 72 + quad * 8];
            bf16x8 pf1 = *(bf16x8*)&ps[(a * 16 + c) * 72 + 32 + quad * 8];
#pragma unroll
            for (int nt = 0; nt < 4; nt++) {
                o[a][nt] = __builtin_amdgcn_mfma_f32_16x16x32_bf16(pf0, vf[nt][0], o[a][nt], 0, 0, 0);
                o[a][nt] = __builtin_amdgcn_mfma_f32_16x16x32_bf16(pf1, vf[nt][1], o[a][nt], 0, 0, 0);
            }
        }
    }
#pragma unroll
    for (int a = 0; a < 4; a++)
#pragma unroll
        for (int r = 0; r < 4; r++) {
#pragma unroll
            for (int off = 1; off < 16; off <<= 1) lsum[a][r] += __shfl_xor(lsum[a][r], off);
        }
#pragma unroll
    for (int a = 0; a < 4; a++)
#pragma unroll
        for (int nt = 0; nt < 4; nt++)
#pragma unroll
            for (int r = 0; r < 4; r++) {
                int l = q0b + a * 16 + quad * 4 + r;
                AO[((long)(b * L_ + l)) * D_ + hq * HD_ + nt * 16 + c] =
                    (bf16)(o[a][nt][r] / lsum[a][r]);
            }
}

// ---------------------------------------------------------------------------
extern "C" void kernel_launch(void* const* d_in, const int* in_sizes, int n_in,
                              void* d_out, int out_size, void* d_ws, size_t ws_size,
                              hipStream_t stream) {
    (void)in_sizes; (void)n_in; (void)out_size; (void)ws_size;
    const float* x  = (const float*)d_in[0];
    const float* wq = (const float*)d_in[1];
    const float* wk = (const float*)d_in[2];
    const float* wv = (const float*)d_in[3];
    const float* wo = (const float*)d_in[4];
    const int* pos  = (const int*)d_in[5];

    bf16* ws    = (bf16*)d_ws;
    bf16* xb    = ws;                   // [3584][2048] bf16 x  (reused as AO)
    bf16* wqkvT = ws + 7340032L;        // [3072][2048]  (wq^T | wk^T | wv^T)
    bf16* woT   = ws + 13631488L;       // [2048][2048]
    bf16* QKV   = ws + 17825792L;       // [3584][3072]
    bf16* Vt    = ws + 28835840L;       // [4][8][64][896]
    bf16* AO    = xb;
    float2* cs  = (float2*)(ws + 30670848L);  // [896][32]

    convert_to_bf16<<<dim3(7168), 256, 0, stream>>>(x, xb);
    rope_cs_kernel<<<dim3(112), dim3(256), 0, stream>>>(pos, cs);

    transpose_cvt<<<dim3(32, 32), 256, 0, stream>>>(wq, (ushort*)wqkvT, 2048, 2048);
    transpose_cvt<<<dim3(8, 32), 256, 0, stream>>>(wk, (ushort*)(wqkvT + 4194304L), 512, 2048);
    transpose_cvt<<<dim3(8, 32), 256, 0, stream>>>(wv, (ushort*)(wqkvT + 5242880L), 512, 2048);
    transpose_cvt<<<dim3(32, 32), 256, 0, stream>>>(wo, (ushort*)woT, 2048, 2048);

    // QKV projection: [3584][2048] x [3072][2048]^T -> [3584][3072] bf16
    gemm224<3, 0><<<dim3(16, 16), 512, 0, stream>>>(xb, wqkvT, QKV, NQKV, D_);

    rope_apply<<<dim3(4480), 256, 0, stream>>>(QKV, cs);

    // V cols of QKV -> Vt[b][h][64][896]
    transpose_u16<<<dim3(1, 14, 32), 256, 0, stream>>>(
        (const ushort*)(QKV + 2560), (ushort*)Vt, 3072, 896,
        896L * 3072, 64, 8L * 57344, 57344);

    attn_kernel<<<dim3(14, 8, 4), 256, 0, stream>>>(QKV, Vt, AO);

    // output projection: [3584][2048] x [2048][2048]^T -> [3584][2048] fp32
    gemm224<2, 1><<<dim3(16, 16), 512, 0, stream>>>(AO, woT, d_out, D_, D_);
}

// Round 8
// 258.881 us; speedup vs baseline: 1.1855x; 1.0301x over previous
//
#include <hip/hip_runtime.h>
#include <hip/hip_bf16.h>
#include <cstdint>

typedef __bf16 bf16;
typedef __bf16 bf16x8 __attribute__((ext_vector_type(8)));
typedef float floatx4 __attribute__((ext_vector_type(4)));

#define B_   4
#define L_   896
#define D_   2048
#define HQ_  32
#define HKV_ 8
#define HD_  64
#define NQKV 3072   /* 2048 q + 512 k + 512 v */
#define M_   3584   /* B_*L_ */

// async global->LDS, 16B per lane. LDS dst must be wave-uniform base + lane*16.
__device__ inline void gl_lds16(const bf16* g, bf16* l) {
    __builtin_amdgcn_global_load_lds(
        (const __attribute__((address_space(1))) void*)g,
        (__attribute__((address_space(3))) void*)l, 16, 0, 0);
}

__device__ inline void barrier_() {
    asm volatile("" ::: "memory");
    __builtin_amdgcn_s_barrier();
    asm volatile("" ::: "memory");
}

// ---------------------------------------------------------------------------
// fp32 -> bf16 (x only). Grid: n/1024 blocks.
// ---------------------------------------------------------------------------
__global__ __launch_bounds__(256) void convert_to_bf16(const float* __restrict__ in,
                                                       bf16* __restrict__ out) {
    long q = (long)blockIdx.x * 256 + threadIdx.x;
    float4 v = ((const float4*)in)[q];
    union { bf16 b[4]; ushort4 u; } w;
    w.b[0] = (bf16)v.x; w.b[1] = (bf16)v.y; w.b[2] = (bf16)v.z; w.b[3] = (bf16)v.w;
    ((ushort4*)out)[q] = w.u;
}

// ---------------------------------------------------------------------------
// RoPE cos/sin table: [L][32] float2
// ---------------------------------------------------------------------------
__global__ __launch_bounds__(256) void rope_cs_kernel(const int* __restrict__ pos_ids,
                                                      float2* __restrict__ cs) {
    int idx = blockIdx.x * 256 + threadIdx.x;
    if (idx >= L_ * 32) return;
    int l = idx >> 5, i = idx & 31;
    float p = (float)pos_ids[l];
    float inv = exp2f(-(float)i * (13.287712379549449f / 32.0f));  // 10000^(-i/32)
    float a = p * inv;
    cs[idx] = make_float2(cosf(a), sinf(a));
}

// ---------------------------------------------------------------------------
// Standalone RoPE, vectorized: 4 pairs (16 B) per thread, in place on
// QKV cols [0,2560). Grid: 3584*320/256 = 4480 blocks.
// ---------------------------------------------------------------------------
__global__ __launch_bounds__(256) void rope_apply(bf16* __restrict__ QKV,
                                                  const float2* __restrict__ cs) {
    int idx = blockIdx.x * 256 + threadIdx.x;   // [0, 3584*320)
    int m = idx / 320, g = idx - m * 320;       // 4-pair group; cols 8g..8g+7
    int l = m % L_;
    int hp = (g * 4) & 31;                      // head-local pair idx of pair0
    const float2* ct = &cs[l * 32 + hp];
    bf16* p = QKV + (long)m * NQKV + g * 8;
    bf16x8 v = *(bf16x8*)p;
    bf16x8 w;
#pragma unroll
    for (int i = 0; i < 4; i++) {
        float2 csv = ct[i];
        float x1 = (float)v[2 * i], x2 = (float)v[2 * i + 1];
        w[2 * i]     = (bf16)(x1 * csv.x - x2 * csv.y);
        w[2 * i + 1] = (bf16)(x1 * csv.y + x2 * csv.x);
    }
    *(bf16x8*)p = w;
}

// ---------------------------------------------------------------------------
// Fused fp32->bf16 + 64x64 tiled transpose. in fp32 [R][C] -> out bf16 [C][R].
// ---------------------------------------------------------------------------
__global__ __launch_bounds__(256) void transpose_cvt(
    const float* __restrict__ in, ushort* __restrict__ out, int C, int R) {
    __shared__ ushort t[64][72];
    int tid = threadIdx.x;
    int tr = tid >> 4, tc = (tid & 15) << 2;
    long r0 = (long)blockIdx.y << 6, c0 = (long)blockIdx.x << 6;
#pragma unroll
    for (int i = 0; i < 4; ++i) {
        float4 v = *(const float4*)&in[(r0 + tr + i * 16) * C + c0 + tc];
        union { bf16 b[4]; ushort4 u; } w;
        w.b[0] = (bf16)v.x; w.b[1] = (bf16)v.y; w.b[2] = (bf16)v.z; w.b[3] = (bf16)v.w;
        *(ushort4*)&t[tr + i * 16][tc] = w.u;
    }
    __syncthreads();
#pragma unroll
    for (int i = 0; i < 4; ++i) {
        ushort4 w;
        w.x = t[tc + 0][tr + i * 16];
        w.y = t[tc + 1][tr + i * 16];
        w.z = t[tc + 2][tr + i * 16];
        w.w = t[tc + 3][tr + i * 16];
        *(ushort4*)&out[(c0 + tr + i * 16) * R + r0 + tc] = w;
    }
}

// ---------------------------------------------------------------------------
// bf16 64x64 tiled transpose (for V -> Vt). z-batch as before.
// ---------------------------------------------------------------------------
__global__ __launch_bounds__(256) void transpose_u16(
    const ushort* __restrict__ in, ushort* __restrict__ out,
    int ld_in, int ld_out, long is1, long is2, long os1, long os2) {
    __shared__ ushort t[64][72];
    int z = blockIdx.z;
    const ushort* ip = in + (long)(z >> 3) * is1 + (long)(z & 7) * is2;
    ushort* op = out + (long)(z >> 3) * os1 + (long)(z & 7) * os2;
    int tid = threadIdx.x;
    int tr = tid >> 4, tc = (tid & 15) << 2;
    long r0 = (long)blockIdx.y << 6, c0 = (long)blockIdx.x << 6;
#pragma unroll
    for (int i = 0; i < 4; ++i) {
        ushort4 v = *(const ushort4*)&ip[(r0 + tr + i * 16) * ld_in + c0 + tc];
        *(ushort4*)&t[tr + i * 16][tc] = v;
    }
    __syncthreads();
#pragma unroll
    for (int i = 0; i < 4; ++i) {
        ushort4 w;
        w.x = t[tc + 0][tr + i * 16];
        w.y = t[tc + 1][tr + i * 16];
        w.z = t[tc + 2][tr + i * 16];
        w.w = t[tc + 3][tr + i * 16];
        *(ushort4*)&op[(c0 + tr + i * 16) * ld_out + r0 + tc] = w;
    }
}

// ===========================================================================
// gemm224<JF,OUTF32>: unchanged (verified round 6). Full 256-block fill.
// ===========================================================================
template <int JF, int OUTF32>
__global__ __launch_bounds__(512, 2) void gemm224(
    const bf16* __restrict__ A, const bf16* __restrict__ Bt, void* __restrict__ C,
    int Ntot, int Ktot) {
    __shared__ bf16 ldsA[2][224 * 64];
    __shared__ bf16 ldsB[2][JF * 64 * 64];
    const int tid = threadIdx.x;
    const int lane = tid & 63;
    const int quad = lane >> 4, l16 = lane & 15;
    const int w = tid >> 6;
    const int wr = w >> 2, wc = w & 3;

    const int gx = gridDim.x;
    const int nwg = gx * gridDim.y;
    int orig = blockIdx.y * gx + blockIdx.x;
    int q8 = nwg >> 3, r8 = nwg & 7;
    int xcd = orig & 7, lid = orig >> 3;
    int wg = (xcd < r8 ? xcd * (q8 + 1) : r8 * (q8 + 1) + (xcd - r8) * q8) + lid;
    const long m0 = (long)(wg / gx) * 224;
    const long n0 = (long)(wg % gx) * (JF * 64);

    const long rowK = Ktot;
    const int srow = tid >> 3;
    const int scol = ((tid & 7) ^ (srow & 7)) << 3;
    const bf16* baseA = A  + (m0 + srow) * rowK + scol;
    const bf16* baseB = Bt + (n0 + srow) * rowK + scol;
    bf16* const dA = (bf16*)ldsA + tid * 8;
    bf16* const dB = (bf16*)ldsB + tid * 8;

    const int m7 = l16 & 7;
    const int col0 = ((0 + quad) ^ m7) << 3;
    const int col1 = ((4 + quad) ^ m7) << 3;
    const int abase = wr * 112 + l16;
    const int bbase = wc * (JF * 16) + l16;

    floatx4 acc[7][JF];
#pragma unroll
    for (int i = 0; i < 7; ++i)
#pragma unroll
        for (int j = 0; j < JF; ++j)
#pragma unroll
            for (int r = 0; r < 4; ++r) acc[i][j][r] = 0.f;

    bf16x8 af0[4][2], af1[3][2], bq[JF][2];

    const int T = Ktot >> 6;

    {
        gl_lds16(baseA,              dA);
        gl_lds16(baseA + 64 * rowK,  dA + 4096);
        gl_lds16(baseA + 128 * rowK, dA + 8192);
        if (tid < 256) gl_lds16(baseA + 192 * rowK, dA + 12288);
#pragma unroll
        for (int r = 0; r < JF; ++r) gl_lds16(baseB + r * 64 * rowK, dB + r * 4096);
#pragma unroll
        for (int r = 0; r < JF; ++r) gl_lds16(baseB + 64 + r * 64 * rowK,
                                              dB + JF * 4096 + r * 4096);
    }
    if (JF == 3) asm volatile("s_waitcnt vmcnt(3)" ::: "memory");
    else         asm volatile("s_waitcnt vmcnt(2)" ::: "memory");
    barrier_();

    for (int t = 0; t < T; ++t) {
        const int cur = t & 1, nxt = cur ^ 1;
        const bf16* pa = &ldsA[cur][0];
        const bf16* pb = &ldsB[cur][0];
        const long koff  = (long)(t + 1) * 64;
        const long koff2 = (long)(t + 2) * 64;

#pragma unroll
        for (int i = 0; i < 4; ++i) {
            const bf16* rp = &pa[(abase + i * 16) * 64];
            af0[i][0] = *(const bf16x8*)&rp[col0];
            af0[i][1] = *(const bf16x8*)&rp[col1];
        }
#pragma unroll
        for (int j = 0; j < JF; ++j) {
            const bf16* rp = &pb[(bbase + j * 16) * 64];
            bq[j][0] = *(const bf16x8*)&rp[col0];
            bq[j][1] = *(const bf16x8*)&rp[col1];
        }
        if (t + 1 < T) {
            const bf16* g = baseA + koff;
            bf16* l = dA + nxt * (224 * 64);
            gl_lds16(g,              l);
            gl_lds16(g + 64 * rowK,  l + 4096);
            gl_lds16(g + 128 * rowK, l + 8192);
            if (tid < 256) gl_lds16(g + 192 * rowK, l + 12288);
        }
        barrier_();
        asm volatile("s_waitcnt lgkmcnt(0)" ::: "memory");
        __builtin_amdgcn_sched_barrier(0);
        __builtin_amdgcn_s_setprio(1);
#pragma unroll
        for (int i = 0; i < 4; ++i)
#pragma unroll
            for (int j = 0; j < JF; ++j) {
                floatx4 c = acc[i][j];
                c = __builtin_amdgcn_mfma_f32_16x16x32_bf16(af0[i][0], bq[j][0], c, 0, 0, 0);
                c = __builtin_amdgcn_mfma_f32_16x16x32_bf16(af0[i][1], bq[j][1], c, 0, 0, 0);
                acc[i][j] = c;
            }
        __builtin_amdgcn_s_setprio(0);
        barrier_();

#pragma unroll
        for (int i = 0; i < 3; ++i) {
            const bf16* rp = &pa[(abase + (4 + i) * 16) * 64];
            af1[i][0] = *(const bf16x8*)&rp[col0];
            af1[i][1] = *(const bf16x8*)&rp[col1];
        }
        if (t + 2 < T) {
            const bf16* g = baseB + koff2;
            bf16* l = dB + cur * (JF * 64 * 64);
#pragma unroll
            for (int r = 0; r < JF; ++r) gl_lds16(g + r * 64 * rowK, l + r * 4096);
        }
        barrier_();
        asm volatile("s_waitcnt lgkmcnt(0)" ::: "memory");
        __builtin_amdgcn_sched_barrier(0);
        __builtin_amdgcn_s_setprio(1);
#pragma unroll
        for (int i = 0; i < 3; ++i)
#pragma unroll
            for (int j = 0; j < JF; ++j) {
                floatx4 c = acc[4 + i][j];
                c = __builtin_amdgcn_mfma_f32_16x16x32_bf16(af1[i][0], bq[j][0], c, 0, 0, 0);
                c = __builtin_amdgcn_mfma_f32_16x16x32_bf16(af1[i][1], bq[j][1], c, 0, 0, 0);
                acc[4 + i][j] = c;
            }
        __builtin_amdgcn_s_setprio(0);
        if (t + 2 < T) {
            if (JF == 3) asm volatile("s_waitcnt vmcnt(3)" ::: "memory");
            else         asm volatile("s_waitcnt vmcnt(2)" ::: "memory");
        } else {
            asm volatile("s_waitcnt vmcnt(0)" ::: "memory");
        }
        barrier_();
    }

#pragma unroll
    for (int i = 0; i < 7; ++i)
#pragma unroll
        for (int j = 0; j < JF; ++j)
#pragma unroll
            for (int r = 0; r < 4; ++r) {
                long m = m0 + wr * 112 + i * 16 + quad * 4 + r;
                long n = n0 + wc * (JF * 16) + j * 16 + l16;
                if (OUTF32) ((float*)C)[m * Ntot + n] = acc[i][j][r];
                else        ((bf16*)C)[m * Ntot + n] = (bf16)acc[i][j][r];
            }
}

// ---------------------------------------------------------------------------
// Flash attention, UNIFORM-WORK blocks: each block owns the q-tile PAIR
// (x, 13-x) for one (b,kvh) -> exactly 15 k-tile-units per block, no
// scheduler/CU-pairing assumptions. Grid (7, 8, 4) = 224 blocks, 512 thr.
// 8 waves: wave w -> head kvh*4 + (w>>1), q-rows (w&1)*32 .. +32 (2 a-frags).
// Per k-tile per wave: 16 QK MFMA + 16 PV MFMA, 32 softmax elems.
// Softmax: p = exp2(s * 0.125*log2e) -- bias dropped (constant factor
// cancels in o/lsum; bf16 range ample). Mask applied only on tiles that
// intersect the causal frontier (block-uniform branch).
// LDS = Ks + Vs + 8*Ps[32*72] = 55.3 KB.
// ---------------------------------------------------------------------------
__global__ __launch_bounds__(512) void attn_kernel(
    const bf16* __restrict__ QKV,  // [M][3072]: q(rope'd) | k(rope'd) | v
    const bf16* __restrict__ Vt,   // [B][HKV][64][896]
    bf16* __restrict__ AO) {       // [M][2048]
    __shared__ bf16 Ks[64 * 72];
    __shared__ bf16 Vs[64 * 72];
    __shared__ bf16 Ps[8][32 * 72];
    const int tid  = threadIdx.x;
    const int wid  = tid >> 6, lane = tid & 63;
    const int quad = lane >> 4, c = lane & 15;
    const int b = blockIdx.z, kvh = blockIdx.y;
    const int hq = kvh * 4 + (wid >> 1);
    const int sub = wid & 1;               // q-row half within the 64-row tile
    const int xpair = blockIdx.x;          // 0..6
    bf16* ps = &Ps[wid][0];

    const bf16* Kb = QKV + ((long)(b * L_)) * NQKV + D_ + kvh * HD_;
    const bf16* Vb = Vt + ((long)(b * HKV_ + kvh)) * (HD_ * L_);

    const int srow = tid >> 3, schunk = (tid & 7) << 3;
    const bf16* kp = &Kb[(long)srow * NQKV + schunk];
    const bf16* vp = &Vb[(long)srow * L_ + schunk];

    const floatx4 fzero = {0.f, 0.f, 0.f, 0.f};
    const float C1 = 0.18033688011112042f;   // 0.125 * log2(e)

#pragma unroll 1
    for (int pass = 0; pass < 2; ++pass) {
        const int x = pass == 0 ? xpair : 13 - xpair;
        const int q0b = x * 64;
        const bf16* Qb = QKV + ((long)(b * L_ + q0b + sub * 32)) * NQKV + hq * HD_;

        bf16x8 qf[2][2];
#pragma unroll
        for (int a = 0; a < 2; a++) {
            qf[a][0] = *(const bf16x8*)&Qb[(long)(a * 16 + c) * NQKV + quad * 8];
            qf[a][1] = *(const bf16x8*)&Qb[(long)(a * 16 + c) * NQKV + 32 + quad * 8];
        }

        float lsum[2][4];
        floatx4 o[2][4];
#pragma unroll
        for (int a = 0; a < 2; a++)
#pragma unroll
            for (int r = 0; r < 4; r++) lsum[a][r] = 0.f;
#pragma unroll
        for (int a = 0; a < 2; a++)
#pragma unroll
            for (int nt = 0; nt < 4; nt++)
#pragma unroll
                for (int r = 0; r < 4; r++) o[a][nt][r] = 0.f;

        int fe[2][4];
#pragma unroll
        for (int a = 0; a < 2; a++)
#pragma unroll
            for (int r = 0; r < 4; r++) {
                int l = q0b + sub * 32 + a * 16 + quad * 4 + r;
                fe[a][r] = (l / 7 + 1) * 7;
            }
        const int femin = (q0b / 7 + 1) * 7;           // fe of block's first row
        const int kend  = ((q0b + 63) / 7 + 1) * 7;    // block-max frame end

        // prefetch tile 0 of this pass
        bf16x8 kg = *(const bf16x8*)&kp[0];
        bf16x8 vg = *(const bf16x8*)&vp[0];

        for (int k0 = 0; k0 < kend; k0 += 64) {
            __syncthreads();   // previous tile's reads done before overwrite
            *(bf16x8*)&Ks[srow * 72 + schunk] = kg;
            *(bf16x8*)&Vs[srow * 72 + schunk] = vg;
            __syncthreads();

            // issue next tile's loads (hide latency under this tile's compute)
            const int kn = k0 + 64;
            if (kn < kend) {
                kg = *(const bf16x8*)&kp[(long)kn * NQKV];
                vg = *(const bf16x8*)&vp[kn];
            }

            bf16x8 kf[4][2];
#pragma unroll
            for (int n = 0; n < 4; n++) {
                kf[n][0] = *(bf16x8*)&Ks[(n * 16 + c) * 72 + quad * 8];
                kf[n][1] = *(bf16x8*)&Ks[(n * 16 + c) * 72 + 32 + quad * 8];
            }
            const int masked = (k0 + 64 > femin);
#pragma unroll
            for (int a = 0; a < 2; a++) {
                floatx4 s[4];
#pragma unroll
                for (int n = 0; n < 4; n++) {
                    s[n] = __builtin_amdgcn_mfma_f32_16x16x32_bf16(qf[a][0], kf[n][0], fzero, 0, 0, 0);
                    s[n] = __builtin_amdgcn_mfma_f32_16x16x32_bf16(qf[a][1], kf[n][1], s[n], 0, 0, 0);
                }
                if (masked) {
#pragma unroll
                    for (int n = 0; n < 4; n++) {
                        const int key = k0 + n * 16 + c;
#pragma unroll
                        for (int r = 0; r < 4; r++) {
                            float e = exp2f(s[n][r] * C1);
                            e = (key < fe[a][r]) ? e : 0.f;
                            lsum[a][r] += e;
                            ps[(a * 16 + quad * 4 + r) * 72 + n * 16 + c] = (bf16)e;
                        }
                    }
                } else {
#pragma unroll
                    for (int n = 0; n < 4; n++) {
#pragma unroll
                        for (int r = 0; r < 4; r++) {
                            float e = exp2f(s[n][r] * C1);
                            lsum[a][r] += e;
                            ps[(a * 16 + quad * 4 + r) * 72 + n * 16 + c] = (bf16)e;
                        }
                    }
                }
            }
            bf16x8 vf[4][2];
#pragma unroll
            for (int nt = 0; nt < 4; nt++) {
                vf[nt][0] = *(bf16x8*)&Vs[(nt * 16 + c) * 72 + quad * 8];
                vf[nt][1] = *(bf16x8*)&Vs[(nt * 16 + c) * 72 + 32 + quad * 8];
            }
#pragma unroll
            for (int a = 0; a < 2; a++) {
                bf16x8 pf0 = *(bf16x8*)&ps[(a * 16 + c) * 72 + quad * 8];
                bf16x8 pf1 = *(bf16x8*)&ps[(a * 16 + c) * 72 + 32 + quad * 8];
#pragma unroll
                for (int nt = 0; nt < 4; nt++) {
                    o[a][nt] = __builtin_amdgcn_mfma_f32_16x16x32_bf16(pf0, vf[nt][0], o[a][nt], 0, 0, 0);
                    o[a][nt] = __builtin_amdgcn_mfma_f32_16x16x32_bf16(pf1, vf[nt][1], o[a][nt], 0, 0, 0);
                }
            }
        }
        // cross-lane lsum reduction over the 16 c-lanes
#pragma unroll
        for (int a = 0; a < 2; a++)
#pragma unroll
            for (int r = 0; r < 4; r++) {
#pragma unroll
                for (int off = 1; off < 16; off <<= 1)
                    lsum[a][r] += __shfl_xor(lsum[a][r], off);
            }
#pragma unroll
        for (int a = 0; a < 2; a++)
#pragma unroll
            for (int nt = 0; nt < 4; nt++)
#pragma unroll
                for (int r = 0; r < 4; r++) {
                    int l = q0b + sub * 32 + a * 16 + quad * 4 + r;
                    AO[((long)(b * L_ + l)) * D_ + hq * HD_ + nt * 16 + c] =
                        (bf16)(o[a][nt][r] / lsum[a][r]);
                }
    }
}

// ---------------------------------------------------------------------------
extern "C" void kernel_launch(void* const* d_in, const int* in_sizes, int n_in,
                              void* d_out, int out_size, void* d_ws, size_t ws_size,
                              hipStream_t stream) {
    (void)in_sizes; (void)n_in; (void)out_size; (void)ws_size;
    const float* x  = (const float*)d_in[0];
    const float* wq = (const float*)d_in[1];
    const float* wk = (const float*)d_in[2];
    const float* wv = (const float*)d_in[3];
    const float* wo = (const float*)d_in[4];
    const int* pos  = (const int*)d_in[5];

    bf16* ws    = (bf16*)d_ws;
    bf16* xb    = ws;                   // [3584][2048] bf16 x  (reused as AO)
    bf16* wqkvT = ws + 7340032L;        // [3072][2048]  (wq^T | wk^T | wv^T)
    bf16* woT   = ws + 13631488L;       // [2048][2048]
    bf16* QKV   = ws + 17825792L;       // [3584][3072]
    bf16* Vt    = ws + 28835840L;       // [4][8][64][896]
    bf16* AO    = xb;
    float2* cs  = (float2*)(ws + 30670848L);  // [896][32]

    convert_to_bf16<<<dim3(7168), 256, 0, stream>>>(x, xb);
    rope_cs_kernel<<<dim3(112), dim3(256), 0, stream>>>(pos, cs);

    transpose_cvt<<<dim3(32, 32), 256, 0, stream>>>(wq, (ushort*)wqkvT, 2048, 2048);
    transpose_cvt<<<dim3(8, 32), 256, 0, stream>>>(wk, (ushort*)(wqkvT + 4194304L), 512, 2048);
    transpose_cvt<<<dim3(8, 32), 256, 0, stream>>>(wv, (ushort*)(wqkvT + 5242880L), 512, 2048);
    transpose_cvt<<<dim3(32, 32), 256, 0, stream>>>(wo, (ushort*)woT, 2048, 2048);

    // QKV projection: [3584][2048] x [3072][2048]^T -> [3584][3072] bf16
    gemm224<3, 0><<<dim3(16, 16), 512, 0, stream>>>(xb, wqkvT, QKV, NQKV, D_);

    rope_apply<<<dim3(4480), 256, 0, stream>>>(QKV, cs);

    // V cols of QKV -> Vt[b][h][64][896]
    transpose_u16<<<dim3(1, 14, 32), 256, 0, stream>>>(
        (const ushort*)(QKV + 2560), (ushort*)Vt, 3072, 896,
        896L * 3072, 64, 8L * 57344, 57344);

    attn_kernel<<<dim3(7, 8, 4), 512, 0, stream>>>(QKV, Vt, AO);

    // output projection: [3584][2048] x [2048][2048]^T -> [3584][2048] fp32
    gemm224<2, 1><<<dim3(16, 16), 512, 0, stream>>>(AO, woT, d_out, D_, D_);
}